// Round 11
// baseline (1135.201 us; speedup 1.0000x reference)
//
#include <hip/hip_runtime.h>

// GCN link predictor, fp32 — round 11: revert fusion (r10 showed fused GEMV
// punches holes in the gather pipeline; split keeps memory pipe busy).
// Keep: XCD-replicated deg (r8), ns folded into cedge weights (r9) so gemm is
// a plain streaming GEMM and aggregate needs no norm_src.
//
// ws layout (float units):
//   0        norm_src [N]
//   100000   norm_dst [N]
//   200000   cursor (int) [N]
//   300000   deg_in (int) [N]
//   400000   row_ptr (int) [N+1]
//   500004   cedge (float4) [E]        (src, ns*w_l0, ns*w_l1, ns*w_l2)
//   4500004  hw   [N*64]  (pre-layer0: deg replicas 16N ints + scan scratch)
//   10900004 agg  [N*64]
// total 17300004 floats = 69.2 MB

#define NN 100000
#define NE 1000000
#define NP 100000
#define SCAN_NB 98

__device__ __forceinline__ void row_fma(float4& acc, float xv, const float4& wv) {
    acc.x = fmaf(xv, wv.x, acc.x);
    acc.y = fmaf(xv, wv.y, acc.y);
    acc.z = fmaf(xv, wv.z, acc.z);
    acc.w = fmaf(xv, wv.w, acc.w);
}

// per-XCD replicated degree count: atomics stay in the local (XCD) L2.
__global__ void deg_kernel(const int4* __restrict__ src4, const int4* __restrict__ dst4,
                           int* __restrict__ repl, int E4) {
    int xcc;
    asm volatile("s_getreg_b32 %0, hwreg(HW_REG_XCC_ID)" : "=s"(xcc));
    xcc &= 7;
    int* dout = repl + xcc * NN;
    int* din  = repl + (8 + xcc) * NN;
    int tid = blockIdx.x * blockDim.x + threadIdx.x;
    if (tid < E4) {
        int4 s = src4[tid], d = dst4[tid];
        __hip_atomic_fetch_add(&dout[s.x], 1, __ATOMIC_RELAXED, __HIP_MEMORY_SCOPE_WORKGROUP);
        __hip_atomic_fetch_add(&dout[s.y], 1, __ATOMIC_RELAXED, __HIP_MEMORY_SCOPE_WORKGROUP);
        __hip_atomic_fetch_add(&dout[s.z], 1, __ATOMIC_RELAXED, __HIP_MEMORY_SCOPE_WORKGROUP);
        __hip_atomic_fetch_add(&dout[s.w], 1, __ATOMIC_RELAXED, __HIP_MEMORY_SCOPE_WORKGROUP);
        __hip_atomic_fetch_add(&din[d.x], 1, __ATOMIC_RELAXED, __HIP_MEMORY_SCOPE_WORKGROUP);
        __hip_atomic_fetch_add(&din[d.y], 1, __ATOMIC_RELAXED, __HIP_MEMORY_SCOPE_WORKGROUP);
        __hip_atomic_fetch_add(&din[d.z], 1, __ATOMIC_RELAXED, __HIP_MEMORY_SCOPE_WORKGROUP);
        __hip_atomic_fetch_add(&din[d.w], 1, __ATOMIC_RELAXED, __HIP_MEMORY_SCOPE_WORKGROUP);
    }
}

__global__ void reduce_norm_kernel(const int* __restrict__ repl, float* __restrict__ norm_src,
                                   float* __restrict__ norm_dst, int* __restrict__ deg_in, int n) {
    int i = blockIdx.x * blockDim.x + threadIdx.x;
    if (i < n) {
        int so = 0, si = 0;
#pragma unroll
        for (int x = 0; x < 8; ++x) {
            so += repl[x * NN + i];
            si += repl[(8 + x) * NN + i];
        }
        norm_src[i] = rsqrtf(fmaxf((float)so, 1.0f));
        norm_dst[i] = rsqrtf(fmaxf((float)si, 1.0f));
        deg_in[i] = si;
    }
}

__global__ __launch_bounds__(1024) void scan_block(const int* __restrict__ deg,
                                                   int* __restrict__ tmp_excl,
                                                   int* __restrict__ blocksums, int n) {
    __shared__ int wsums[16];
    const int i = blockIdx.x * 1024 + threadIdx.x;
    const int lane = threadIdx.x & 63, w = threadIdx.x >> 6;
    int v = (i < n) ? deg[i] : 0;
    int s = v;
#pragma unroll
    for (int off = 1; off < 64; off <<= 1) {
        int u = __shfl_up(s, off, 64);
        if (lane >= off) s += u;
    }
    if (lane == 63) wsums[w] = s;
    __syncthreads();
    if (w == 0) {
        int wv = (lane < 16) ? wsums[lane] : 0;
#pragma unroll
        for (int off = 1; off < 16; off <<= 1) {
            int u = __shfl_up(wv, off, 64);
            if (lane >= off) wv += u;
        }
        if (lane < 16) wsums[lane] = wv;
    }
    __syncthreads();
    int excl = s - v + (w > 0 ? wsums[w - 1] : 0);
    if (i < n) tmp_excl[i] = excl;
    if (threadIdx.x == 1023) blocksums[blockIdx.x] = excl + v;
}

__global__ void scan_sums(int* __restrict__ bs, int nb) {
    __shared__ int wtot[2];
    const int t = threadIdx.x;  // 128 threads
    const int lane = t & 63, w = t >> 6;
    int v = (t < nb) ? bs[t] : 0;
    int s = v;
#pragma unroll
    for (int off = 1; off < 64; off <<= 1) {
        int u = __shfl_up(s, off, 64);
        if (lane >= off) s += u;
    }
    if (lane == 63) wtot[w] = s;
    __syncthreads();
    int excl = s - v + (w == 1 ? wtot[0] : 0);
    if (t < nb) bs[t] = excl;
}

__global__ __launch_bounds__(1024) void scan_apply(const int* __restrict__ tmp_excl,
                                                   const int* __restrict__ bs,
                                                   int* __restrict__ row_ptr,
                                                   int* __restrict__ cursor, int n) {
    const int i = blockIdx.x * 1024 + threadIdx.x;
    if (i < n) {
        int r = tmp_excl[i] + bs[blockIdx.x];
        row_ptr[i] = r;
        cursor[i] = r;
    }
    if (i == 0) row_ptr[n] = NE;
}

// pack each edge into its dst row; fold norm_src[src] into all 3 layer weights.
__global__ void csr_fill(const int* __restrict__ src, const int* __restrict__ dst,
                         const float* __restrict__ ew, const float* __restrict__ norm_src,
                         int* __restrict__ cursor, float4* __restrict__ cedge, int E) {
    int tid = blockIdx.x * blockDim.x + threadIdx.x;
    int stride = gridDim.x * blockDim.x;
    for (int e = tid; e < E; e += stride) {
        int s = src[e];
        int d = dst[e];
        float nsv = norm_src[s];
        int slot = atomicAdd(&cursor[d], 1);
        float4 c;
        c.x = __int_as_float(s);
        c.y = ew[e] * nsv;
        c.z = ew[NE + e] * nsv;
        c.w = ew[2 * NE + e] * nsv;
        cedge[slot] = c;
    }
}

// Pure-gather CSR aggregation, one wave per dst node, 8-deep batched loads.
//  RELU=1: out = relu(a*norm_dst + bias)     RELU=0: out = a*norm_dst + bias (final)
// (norm_src already folded into cedge weights)
template <int WSEL, bool RELU>
__global__ __launch_bounds__(256) void aggregate(const float* __restrict__ hw,
                                                 const float4* __restrict__ cedge,
                                                 const int* __restrict__ row_ptr,
                                                 const float* __restrict__ norm_dst,
                                                 const float* __restrict__ bias,
                                                 float* __restrict__ outx, int n) {
    const int lane = threadIdx.x & 63;
    const int gw = (blockIdx.x * blockDim.x + threadIdx.x) >> 6;
    const int nw = (gridDim.x * blockDim.x) >> 6;
    const float blane = bias[lane];
    for (int node = gw; node < n; node += nw) {
        int beg = row_ptr[node], end = row_ptr[node + 1];
        float a0 = 0.f, a1 = 0.f, a2 = 0.f, a3 = 0.f;
        int i = beg;
        for (; i + 7 < end; i += 8) {
            float4 c0 = cedge[i + 0], c1 = cedge[i + 1], c2 = cedge[i + 2], c3 = cedge[i + 3];
            float4 c4 = cedge[i + 4], c5 = cedge[i + 5], c6 = cedge[i + 6], c7 = cedge[i + 7];
            float h0 = hw[__float_as_int(c0.x) * 64 + lane];
            float h1 = hw[__float_as_int(c1.x) * 64 + lane];
            float h2 = hw[__float_as_int(c2.x) * 64 + lane];
            float h3 = hw[__float_as_int(c3.x) * 64 + lane];
            float h4 = hw[__float_as_int(c4.x) * 64 + lane];
            float h5 = hw[__float_as_int(c5.x) * 64 + lane];
            float h6 = hw[__float_as_int(c6.x) * 64 + lane];
            float h7 = hw[__float_as_int(c7.x) * 64 + lane];
            a0 = fmaf(h0, (WSEL == 0) ? c0.y : (WSEL == 1) ? c0.z : c0.w, a0);
            a1 = fmaf(h1, (WSEL == 0) ? c1.y : (WSEL == 1) ? c1.z : c1.w, a1);
            a2 = fmaf(h2, (WSEL == 0) ? c2.y : (WSEL == 1) ? c2.z : c2.w, a2);
            a3 = fmaf(h3, (WSEL == 0) ? c3.y : (WSEL == 1) ? c3.z : c3.w, a3);
            a0 = fmaf(h4, (WSEL == 0) ? c4.y : (WSEL == 1) ? c4.z : c4.w, a0);
            a1 = fmaf(h5, (WSEL == 0) ? c5.y : (WSEL == 1) ? c5.z : c5.w, a1);
            a2 = fmaf(h6, (WSEL == 0) ? c6.y : (WSEL == 1) ? c6.z : c6.w, a2);
            a3 = fmaf(h7, (WSEL == 0) ? c7.y : (WSEL == 1) ? c7.z : c7.w, a3);
        }
        for (; i + 1 < end; i += 2) {
            float4 c0 = cedge[i], c1 = cedge[i + 1];
            float h0 = hw[__float_as_int(c0.x) * 64 + lane];
            float h1 = hw[__float_as_int(c1.x) * 64 + lane];
            a0 = fmaf(h0, (WSEL == 0) ? c0.y : (WSEL == 1) ? c0.z : c0.w, a0);
            a1 = fmaf(h1, (WSEL == 0) ? c1.y : (WSEL == 1) ? c1.z : c1.w, a1);
        }
        if (i < end) {
            float4 c0 = cedge[i];
            float h0 = hw[__float_as_int(c0.x) * 64 + lane];
            a0 = fmaf(h0, (WSEL == 0) ? c0.y : (WSEL == 1) ? c0.z : c0.w, a0);
        }
        float a = (a0 + a1) + (a2 + a3);
        float t = fmaf(a, norm_dst[node], blane);
        if (RELU) t = fmaxf(t, 0.f);
        outx[node * 64 + lane] = t;
    }
}

// Streaming 64-row GEMM tile: out = in @ W. W in LDS (staged once, one barrier),
// X from global with explicit next-k4 register prefetch (keeps >=4 loads in flight
// regardless of scheduler mood — guards against the r8 regalloc serialization).
template <int K>
__global__ __launch_bounds__(256) void gemm_tile(const float* __restrict__ in,
                                                 const float* __restrict__ W,
                                                 float* __restrict__ out, int n) {
    __shared__ float Ws[K * 64];
    const int tid = threadIdx.x;
    for (int i = tid; i < K * 16; i += 256) ((float4*)Ws)[i] = ((const float4*)W)[i];
    __syncthreads();  // only barrier

    const int tr = tid >> 4, tc = tid & 15;
    const int row0 = blockIdx.x * 64 + tr * 4;
    const float* xr0 = in + (size_t)min(row0 + 0, n - 1) * K;
    const float* xr1 = in + (size_t)min(row0 + 1, n - 1) * K;
    const float* xr2 = in + (size_t)min(row0 + 2, n - 1) * K;
    const float* xr3 = in + (size_t)min(row0 + 3, n - 1) * K;

    float4 acc0 = {0, 0, 0, 0}, acc1 = {0, 0, 0, 0}, acc2 = {0, 0, 0, 0}, acc3 = {0, 0, 0, 0};
    float4 cur0 = *(const float4*)&xr0[0];
    float4 cur1 = *(const float4*)&xr1[0];
    float4 cur2 = *(const float4*)&xr2[0];
    float4 cur3 = *(const float4*)&xr3[0];
#pragma unroll
    for (int k4 = 0; k4 < K / 4; ++k4) {
        float4 nxt0, nxt1, nxt2, nxt3;
        if (k4 + 1 < K / 4) {
            const int kb = (k4 + 1) * 4;
            nxt0 = *(const float4*)&xr0[kb];
            nxt1 = *(const float4*)&xr1[kb];
            nxt2 = *(const float4*)&xr2[kb];
            nxt3 = *(const float4*)&xr3[kb];
        }
        const int kb = k4 * 4;
        const float* wb = &Ws[kb * 64 + tc * 4];
        float4 wk;
        wk = *(const float4*)(wb);
        row_fma(acc0, cur0.x, wk); row_fma(acc1, cur1.x, wk); row_fma(acc2, cur2.x, wk); row_fma(acc3, cur3.x, wk);
        wk = *(const float4*)(wb + 64);
        row_fma(acc0, cur0.y, wk); row_fma(acc1, cur1.y, wk); row_fma(acc2, cur2.y, wk); row_fma(acc3, cur3.y, wk);
        wk = *(const float4*)(wb + 128);
        row_fma(acc0, cur0.z, wk); row_fma(acc1, cur1.z, wk); row_fma(acc2, cur2.z, wk); row_fma(acc3, cur3.z, wk);
        wk = *(const float4*)(wb + 192);
        row_fma(acc0, cur0.w, wk); row_fma(acc1, cur1.w, wk); row_fma(acc2, cur2.w, wk); row_fma(acc3, cur3.w, wk);
        cur0 = nxt0; cur1 = nxt1; cur2 = nxt2; cur3 = nxt3;
    }

#pragma unroll
    for (int i = 0; i < 4; ++i) {
        int row = row0 + i;
        if (row < n) {
            float4 o = (i == 0) ? acc0 : (i == 1) ? acc1 : (i == 2) ? acc2 : acc3;
            *(float4*)&out[row * 64 + tc * 4] = o;
        }
    }
}

#define ZST 76  // Zs row stride

// 64 pairs per block (grid = 3125): Z staged in LDS, P0/P1 from global (L1-broadcast).
__global__ __launch_bounds__(256) void mlp_tile(const float* __restrict__ hfin,
                                                const float* __restrict__ P0,
                                                const float* __restrict__ pb0,
                                                const float* __restrict__ P1,
                                                const float* __restrict__ pb1,
                                                const float* __restrict__ P2,
                                                const float* __restrict__ pb2,
                                                const int* __restrict__ pos_src,
                                                const int* __restrict__ pos_dst,
                                                const int* __restrict__ neg_src,
                                                const int* __restrict__ neg_dst,
                                                float* __restrict__ out, int P) {
    __shared__ float Zs[64][ZST];
    __shared__ float pb0s[64], pb1s[64], P2s[64];
    __shared__ int pas[64], pbs[64];
    const int tid = threadIdx.x;
    const int base = blockIdx.x << 6;
    if (tid < 64) {
        pb0s[tid] = pb0[tid];
        pb1s[tid] = pb1[tid];
        P2s[tid] = P2[tid];
        int p = base + tid;
        pas[tid] = (p < P) ? pos_src[p] : neg_src[p - P];
        pbs[tid] = (p < P) ? pos_dst[p] : neg_dst[p - P];
    }
    const float pb2v = pb2[0];
    const int lane = tid & 63, w = tid >> 6;
    const int tr = tid >> 4, tc = tid & 15;
    __syncthreads();

    // gather + product: wave w owns pairs [w*16, w*16+16); 16 loads in flight per round
    {
        const int pbase = w * 16;
#pragma unroll
        for (int r = 0; r < 2; ++r) {
            const int p0 = pbase + r * 8;
            int a0 = pas[p0 + 0], b0 = pbs[p0 + 0];
            int a1 = pas[p0 + 1], b1 = pbs[p0 + 1];
            int a2 = pas[p0 + 2], b2 = pbs[p0 + 2];
            int a3 = pas[p0 + 3], b3 = pbs[p0 + 3];
            int a4 = pas[p0 + 4], b4 = pbs[p0 + 4];
            int a5 = pas[p0 + 5], b5 = pbs[p0 + 5];
            int a6 = pas[p0 + 6], b6 = pbs[p0 + 6];
            int a7 = pas[p0 + 7], b7 = pbs[p0 + 7];
            float ha0 = hfin[a0 * 64 + lane], hb0 = hfin[b0 * 64 + lane];
            float ha1 = hfin[a1 * 64 + lane], hb1 = hfin[b1 * 64 + lane];
            float ha2 = hfin[a2 * 64 + lane], hb2 = hfin[b2 * 64 + lane];
            float ha3 = hfin[a3 * 64 + lane], hb3 = hfin[b3 * 64 + lane];
            float ha4 = hfin[a4 * 64 + lane], hb4 = hfin[b4 * 64 + lane];
            float ha5 = hfin[a5 * 64 + lane], hb5 = hfin[b5 * 64 + lane];
            float ha6 = hfin[a6 * 64 + lane], hb6 = hfin[b6 * 64 + lane];
            float ha7 = hfin[a7 * 64 + lane], hb7 = hfin[b7 * 64 + lane];
            Zs[p0 + 0][lane] = ha0 * hb0;
            Zs[p0 + 1][lane] = ha1 * hb1;
            Zs[p0 + 2][lane] = ha2 * hb2;
            Zs[p0 + 3][lane] = ha3 * hb3;
            Zs[p0 + 4][lane] = ha4 * hb4;
            Zs[p0 + 5][lane] = ha5 * hb5;
            Zs[p0 + 6][lane] = ha6 * hb6;
            Zs[p0 + 7][lane] = ha7 * hb7;
        }
    }
    __syncthreads();

    // layer 0: Z1 = relu(Z @ P0 + pb0)
    float4 acc0, acc1, acc2, acc3;
    {
        float4 binit = *(const float4*)&pb0s[tc * 4];
        acc0 = binit; acc1 = binit; acc2 = binit; acc3 = binit;
    }
#pragma unroll 4
    for (int k4 = 0; k4 < 16; ++k4) {
        const int kb = k4 * 4;
        float4 xv0 = *(const float4*)&Zs[tr * 4 + 0][kb];
        float4 xv1 = *(const float4*)&Zs[tr * 4 + 1][kb];
        float4 xv2 = *(const float4*)&Zs[tr * 4 + 2][kb];
        float4 xv3 = *(const float4*)&Zs[tr * 4 + 3][kb];
        const float* wb = &P0[kb * 64 + tc * 4];
        float4 wk;
        wk = *(const float4*)(wb);
        row_fma(acc0, xv0.x, wk); row_fma(acc1, xv1.x, wk); row_fma(acc2, xv2.x, wk); row_fma(acc3, xv3.x, wk);
        wk = *(const float4*)(wb + 64);
        row_fma(acc0, xv0.y, wk); row_fma(acc1, xv1.y, wk); row_fma(acc2, xv2.y, wk); row_fma(acc3, xv3.y, wk);
        wk = *(const float4*)(wb + 128);
        row_fma(acc0, xv0.z, wk); row_fma(acc1, xv1.z, wk); row_fma(acc2, xv2.z, wk); row_fma(acc3, xv3.z, wk);
        wk = *(const float4*)(wb + 192);
        row_fma(acc0, xv0.w, wk); row_fma(acc1, xv1.w, wk); row_fma(acc2, xv2.w, wk); row_fma(acc3, xv3.w, wk);
    }
    __syncthreads();
#pragma unroll
    for (int i = 0; i < 4; ++i) {
        float4 o = (i == 0) ? acc0 : (i == 1) ? acc1 : (i == 2) ? acc2 : acc3;
        o.x = fmaxf(o.x, 0.f); o.y = fmaxf(o.y, 0.f); o.z = fmaxf(o.z, 0.f); o.w = fmaxf(o.w, 0.f);
        *(float4*)&Zs[tr * 4 + i][tc * 4] = o;
    }
    __syncthreads();

    // layer 1: Z2 = relu(Z1 @ P1 + pb1)
    {
        float4 binit = *(const float4*)&pb1s[tc * 4];
        acc0 = binit; acc1 = binit; acc2 = binit; acc3 = binit;
    }
#pragma unroll 4
    for (int k4 = 0; k4 < 16; ++k4) {
        const int kb = k4 * 4;
        float4 xv0 = *(const float4*)&Zs[tr * 4 + 0][kb];
        float4 xv1 = *(const float4*)&Zs[tr * 4 + 1][kb];
        float4 xv2 = *(const float4*)&Zs[tr * 4 + 2][kb];
        float4 xv3 = *(const float4*)&Zs[tr * 4 + 3][kb];
        const float* wb = &P1[kb * 64 + tc * 4];
        float4 wk;
        wk = *(const float4*)(wb);
        row_fma(acc0, xv0.x, wk); row_fma(acc1, xv1.x, wk); row_fma(acc2, xv2.x, wk); row_fma(acc3, xv3.x, wk);
        wk = *(const float4*)(wb + 64);
        row_fma(acc0, xv0.y, wk); row_fma(acc1, xv1.y, wk); row_fma(acc2, xv2.y, wk); row_fma(acc3, xv3.y, wk);
        wk = *(const float4*)(wb + 128);
        row_fma(acc0, xv0.z, wk); row_fma(acc1, xv1.z, wk); row_fma(acc2, xv2.z, wk); row_fma(acc3, xv3.z, wk);
        wk = *(const float4*)(wb + 192);
        row_fma(acc0, xv0.w, wk); row_fma(acc1, xv1.w, wk); row_fma(acc2, xv2.w, wk); row_fma(acc3, xv3.w, wk);
    }
    __syncthreads();
#pragma unroll
    for (int i = 0; i < 4; ++i) {
        float4 o = (i == 0) ? acc0 : (i == 1) ? acc1 : (i == 2) ? acc2 : acc3;
        o.x = fmaxf(o.x, 0.f); o.y = fmaxf(o.y, 0.f); o.z = fmaxf(o.z, 0.f); o.w = fmaxf(o.w, 0.f);
        *(float4*)&Zs[tr * 4 + i][tc * 4] = o;
    }
    __syncthreads();

    // final GEMV: out[p] = Z2[p] . P2 + pb2
    {
        int p = tid >> 2, kq = tid & 3;
        float s = 0.f;
#pragma unroll
        for (int i = 0; i < 16; ++i) s = fmaf(Zs[p][kq * 16 + i], P2s[kq * 16 + i], s);
        s += __shfl_xor(s, 1, 64);
        s += __shfl_xor(s, 2, 64);
        if (kq == 0) out[base + p] = s + pb2v;
    }
}

extern "C" void kernel_launch(void* const* d_in, const int* in_sizes, int n_in,
                              void* d_out, int out_size, void* d_ws, size_t ws_size,
                              hipStream_t stream) {
    const float* x     = (const float*)d_in[0];
    const float* ew    = (const float*)d_in[1];  // (3, E)
    const int* src     = (const int*)d_in[2];
    const int* dst     = (const int*)d_in[3];
    const int* pos_src = (const int*)d_in[4];
    const int* pos_dst = (const int*)d_in[5];
    const int* neg_src = (const int*)d_in[6];
    const int* neg_dst = (const int*)d_in[7];
    const float* W0    = (const float*)d_in[8];
    const float* b0    = (const float*)d_in[9];
    const float* W1    = (const float*)d_in[10];
    const float* b1    = (const float*)d_in[11];
    const float* W2    = (const float*)d_in[12];
    const float* b2    = (const float*)d_in[13];
    const float* P0    = (const float*)d_in[14];
    const float* pb0   = (const float*)d_in[15];
    const float* P1    = (const float*)d_in[16];
    const float* pb1   = (const float*)d_in[17];
    const float* P2    = (const float*)d_in[18];
    const float* pb2   = (const float*)d_in[19];
    float* out = (float*)d_out;

    float* ws = (float*)d_ws;
    float* norm_src = ws;                     // N
    float* norm_dst = ws + 100000;            // N
    int* cursor     = (int*)(ws + 200000);    // N
    int* deg_in     = (int*)(ws + 300000);    // N
    int* row_ptr    = (int*)(ws + 400000);    // N+1
    float4* cedge   = (float4*)(ws + 500004); // E
    float* hw       = ws + 4500004;           // N*64
    float* agg      = ws + 10900004;          // N*64

    // pre-layer0 scratch inside hw region (not yet live)
    int* repl      = (int*)hw;            // 16*NN ints: [deg_out x8][deg_in x8]
    int* tmp_excl  = (int*)hw + 16 * NN;  // NN
    int* blocksums = (int*)hw + 17 * NN;  // SCAN_NB

    hipMemsetAsync(repl, 0, 16 * NN * sizeof(int), stream);
    deg_kernel<<<(NE / 4 + 255) / 256, 256, 0, stream>>>((const int4*)src, (const int4*)dst,
                                                         repl, NE / 4);
    reduce_norm_kernel<<<(NN + 255) / 256, 256, 0, stream>>>(repl, norm_src, norm_dst, deg_in, NN);
    scan_block<<<SCAN_NB, 1024, 0, stream>>>(deg_in, tmp_excl, blocksums, NN);
    scan_sums<<<1, 128, 0, stream>>>(blocksums, SCAN_NB);
    scan_apply<<<SCAN_NB, 1024, 0, stream>>>(tmp_excl, blocksums, row_ptr, cursor, NN);
    csr_fill<<<2048, 256, 0, stream>>>(src, dst, ew, norm_src, cursor, cedge, NE);

    const int NT = (NN + 63) / 64;  // 1563 tiles

    // layer 0: hw = x @ W0 ; agg = relu((sum cw0*hw[src])*nd + b0)
    gemm_tile<128><<<NT, 256, 0, stream>>>(x, W0, hw, NN);
    aggregate<0, true><<<4096, 256, 0, stream>>>(hw, cedge, row_ptr, norm_dst, b0, agg, NN);
    // layer 1
    gemm_tile<64><<<NT, 256, 0, stream>>>(agg, W1, hw, NN);
    aggregate<1, true><<<4096, 256, 0, stream>>>(hw, cedge, row_ptr, norm_dst, b1, agg, NN);
    // layer 2 (final, no relu)
    gemm_tile<64><<<NT, 256, 0, stream>>>(agg, W2, hw, NN);
    aggregate<2, false><<<4096, 256, 0, stream>>>(hw, cedge, row_ptr, norm_dst, b2, agg, NN);

    // MLP over pos & neg pairs
    mlp_tile<<<(2 * NP) / 64, 256, 0, stream>>>(agg, P0, pb0, P1, pb1, P2, pb2,
                                                pos_src, pos_dst, neg_src, neg_dst, out, NP);
}

// Round 12
// 515.255 us; speedup vs baseline: 2.2032x; 2.2032x over previous
//
#include <hip/hip_runtime.h>

// GCN link predictor, fp32 — round 12: recover from r11 spill disaster.
//  * gemm_tile: exact r7 loop body (unroll 4, NO manual prefetch — r11's
//    prefetch+full-unroll spilled: VGPR 256, 1.4GB scratch traffic, 690us)
//  * mlp_tile: 32 pairs/block (grid 6250, LDS ~10KB -> ~8 blocks/CU,
//    single 16-load gather round per wave)
//  * keep: XCD-replicated deg (r8), ns folded into cedge (r9), split layers (r11)
//
// ws layout (float units):
//   0        norm_src [N]
//   100000   norm_dst [N]
//   200000   cursor (int) [N]
//   300000   deg_in (int) [N]
//   400000   row_ptr (int) [N+1]
//   500004   cedge (float4) [E]        (src, ns*w_l0, ns*w_l1, ns*w_l2)
//   4500004  hw   [N*64]  (pre-layer0: deg replicas 16N ints + scan scratch)
//   10900004 agg  [N*64]
// total 17300004 floats = 69.2 MB

#define NN 100000
#define NE 1000000
#define NP 100000
#define SCAN_NB 98

__device__ __forceinline__ void row_fma(float4& acc, float xv, const float4& wv) {
    acc.x = fmaf(xv, wv.x, acc.x);
    acc.y = fmaf(xv, wv.y, acc.y);
    acc.z = fmaf(xv, wv.z, acc.z);
    acc.w = fmaf(xv, wv.w, acc.w);
}

// per-XCD replicated degree count: atomics stay in the local (XCD) L2.
__global__ void deg_kernel(const int4* __restrict__ src4, const int4* __restrict__ dst4,
                           int* __restrict__ repl, int E4) {
    int xcc;
    asm volatile("s_getreg_b32 %0, hwreg(HW_REG_XCC_ID)" : "=s"(xcc));
    xcc &= 7;
    int* dout = repl + xcc * NN;
    int* din  = repl + (8 + xcc) * NN;
    int tid = blockIdx.x * blockDim.x + threadIdx.x;
    if (tid < E4) {
        int4 s = src4[tid], d = dst4[tid];
        __hip_atomic_fetch_add(&dout[s.x], 1, __ATOMIC_RELAXED, __HIP_MEMORY_SCOPE_WORKGROUP);
        __hip_atomic_fetch_add(&dout[s.y], 1, __ATOMIC_RELAXED, __HIP_MEMORY_SCOPE_WORKGROUP);
        __hip_atomic_fetch_add(&dout[s.z], 1, __ATOMIC_RELAXED, __HIP_MEMORY_SCOPE_WORKGROUP);
        __hip_atomic_fetch_add(&dout[s.w], 1, __ATOMIC_RELAXED, __HIP_MEMORY_SCOPE_WORKGROUP);
        __hip_atomic_fetch_add(&din[d.x], 1, __ATOMIC_RELAXED, __HIP_MEMORY_SCOPE_WORKGROUP);
        __hip_atomic_fetch_add(&din[d.y], 1, __ATOMIC_RELAXED, __HIP_MEMORY_SCOPE_WORKGROUP);
        __hip_atomic_fetch_add(&din[d.z], 1, __ATOMIC_RELAXED, __HIP_MEMORY_SCOPE_WORKGROUP);
        __hip_atomic_fetch_add(&din[d.w], 1, __ATOMIC_RELAXED, __HIP_MEMORY_SCOPE_WORKGROUP);
    }
}

__global__ void reduce_norm_kernel(const int* __restrict__ repl, float* __restrict__ norm_src,
                                   float* __restrict__ norm_dst, int* __restrict__ deg_in, int n) {
    int i = blockIdx.x * blockDim.x + threadIdx.x;
    if (i < n) {
        int so = 0, si = 0;
#pragma unroll
        for (int x = 0; x < 8; ++x) {
            so += repl[x * NN + i];
            si += repl[(8 + x) * NN + i];
        }
        norm_src[i] = rsqrtf(fmaxf((float)so, 1.0f));
        norm_dst[i] = rsqrtf(fmaxf((float)si, 1.0f));
        deg_in[i] = si;
    }
}

__global__ __launch_bounds__(1024) void scan_block(const int* __restrict__ deg,
                                                   int* __restrict__ tmp_excl,
                                                   int* __restrict__ blocksums, int n) {
    __shared__ int wsums[16];
    const int i = blockIdx.x * 1024 + threadIdx.x;
    const int lane = threadIdx.x & 63, w = threadIdx.x >> 6;
    int v = (i < n) ? deg[i] : 0;
    int s = v;
#pragma unroll
    for (int off = 1; off < 64; off <<= 1) {
        int u = __shfl_up(s, off, 64);
        if (lane >= off) s += u;
    }
    if (lane == 63) wsums[w] = s;
    __syncthreads();
    if (w == 0) {
        int wv = (lane < 16) ? wsums[lane] : 0;
#pragma unroll
        for (int off = 1; off < 16; off <<= 1) {
            int u = __shfl_up(wv, off, 64);
            if (lane >= off) wv += u;
        }
        if (lane < 16) wsums[lane] = wv;
    }
    __syncthreads();
    int excl = s - v + (w > 0 ? wsums[w - 1] : 0);
    if (i < n) tmp_excl[i] = excl;
    if (threadIdx.x == 1023) blocksums[blockIdx.x] = excl + v;
}

__global__ void scan_sums(int* __restrict__ bs, int nb) {
    __shared__ int wtot[2];
    const int t = threadIdx.x;  // 128 threads
    const int lane = t & 63, w = t >> 6;
    int v = (t < nb) ? bs[t] : 0;
    int s = v;
#pragma unroll
    for (int off = 1; off < 64; off <<= 1) {
        int u = __shfl_up(s, off, 64);
        if (lane >= off) s += u;
    }
    if (lane == 63) wtot[w] = s;
    __syncthreads();
    int excl = s - v + (w == 1 ? wtot[0] : 0);
    if (t < nb) bs[t] = excl;
}

__global__ __launch_bounds__(1024) void scan_apply(const int* __restrict__ tmp_excl,
                                                   const int* __restrict__ bs,
                                                   int* __restrict__ row_ptr,
                                                   int* __restrict__ cursor, int n) {
    const int i = blockIdx.x * 1024 + threadIdx.x;
    if (i < n) {
        int r = tmp_excl[i] + bs[blockIdx.x];
        row_ptr[i] = r;
        cursor[i] = r;
    }
    if (i == 0) row_ptr[n] = NE;
}

// pack each edge into its dst row; fold norm_src[src] into all 3 layer weights.
__global__ void csr_fill(const int* __restrict__ src, const int* __restrict__ dst,
                         const float* __restrict__ ew, const float* __restrict__ norm_src,
                         int* __restrict__ cursor, float4* __restrict__ cedge, int E) {
    int tid = blockIdx.x * blockDim.x + threadIdx.x;
    int stride = gridDim.x * blockDim.x;
    for (int e = tid; e < E; e += stride) {
        int s = src[e];
        int d = dst[e];
        float nsv = norm_src[s];
        int slot = atomicAdd(&cursor[d], 1);
        float4 c;
        c.x = __int_as_float(s);
        c.y = ew[e] * nsv;
        c.z = ew[NE + e] * nsv;
        c.w = ew[2 * NE + e] * nsv;
        cedge[slot] = c;
    }
}

// Pure-gather CSR aggregation, one wave per dst node, 8-deep batched loads.
//  RELU=1: out = relu(a*norm_dst + bias)     RELU=0: out = a*norm_dst + bias (final)
template <int WSEL, bool RELU>
__global__ __launch_bounds__(256) void aggregate(const float* __restrict__ hw,
                                                 const float4* __restrict__ cedge,
                                                 const int* __restrict__ row_ptr,
                                                 const float* __restrict__ norm_dst,
                                                 const float* __restrict__ bias,
                                                 float* __restrict__ outx, int n) {
    const int lane = threadIdx.x & 63;
    const int gw = (blockIdx.x * blockDim.x + threadIdx.x) >> 6;
    const int nw = (gridDim.x * blockDim.x) >> 6;
    const float blane = bias[lane];
    for (int node = gw; node < n; node += nw) {
        int beg = row_ptr[node], end = row_ptr[node + 1];
        float a0 = 0.f, a1 = 0.f, a2 = 0.f, a3 = 0.f;
        int i = beg;
        for (; i + 7 < end; i += 8) {
            float4 c0 = cedge[i + 0], c1 = cedge[i + 1], c2 = cedge[i + 2], c3 = cedge[i + 3];
            float4 c4 = cedge[i + 4], c5 = cedge[i + 5], c6 = cedge[i + 6], c7 = cedge[i + 7];
            float h0 = hw[__float_as_int(c0.x) * 64 + lane];
            float h1 = hw[__float_as_int(c1.x) * 64 + lane];
            float h2 = hw[__float_as_int(c2.x) * 64 + lane];
            float h3 = hw[__float_as_int(c3.x) * 64 + lane];
            float h4 = hw[__float_as_int(c4.x) * 64 + lane];
            float h5 = hw[__float_as_int(c5.x) * 64 + lane];
            float h6 = hw[__float_as_int(c6.x) * 64 + lane];
            float h7 = hw[__float_as_int(c7.x) * 64 + lane];
            a0 = fmaf(h0, (WSEL == 0) ? c0.y : (WSEL == 1) ? c0.z : c0.w, a0);
            a1 = fmaf(h1, (WSEL == 0) ? c1.y : (WSEL == 1) ? c1.z : c1.w, a1);
            a2 = fmaf(h2, (WSEL == 0) ? c2.y : (WSEL == 1) ? c2.z : c2.w, a2);
            a3 = fmaf(h3, (WSEL == 0) ? c3.y : (WSEL == 1) ? c3.z : c3.w, a3);
            a0 = fmaf(h4, (WSEL == 0) ? c4.y : (WSEL == 1) ? c4.z : c4.w, a0);
            a1 = fmaf(h5, (WSEL == 0) ? c5.y : (WSEL == 1) ? c5.z : c5.w, a1);
            a2 = fmaf(h6, (WSEL == 0) ? c6.y : (WSEL == 1) ? c6.z : c6.w, a2);
            a3 = fmaf(h7, (WSEL == 0) ? c7.y : (WSEL == 1) ? c7.z : c7.w, a3);
        }
        for (; i + 1 < end; i += 2) {
            float4 c0 = cedge[i], c1 = cedge[i + 1];
            float h0 = hw[__float_as_int(c0.x) * 64 + lane];
            float h1 = hw[__float_as_int(c1.x) * 64 + lane];
            a0 = fmaf(h0, (WSEL == 0) ? c0.y : (WSEL == 1) ? c0.z : c0.w, a0);
            a1 = fmaf(h1, (WSEL == 0) ? c1.y : (WSEL == 1) ? c1.z : c1.w, a1);
        }
        if (i < end) {
            float4 c0 = cedge[i];
            float h0 = hw[__float_as_int(c0.x) * 64 + lane];
            a0 = fmaf(h0, (WSEL == 0) ? c0.y : (WSEL == 1) ? c0.z : c0.w, a0);
        }
        float a = (a0 + a1) + (a2 + a3);
        float t = fmaf(a, norm_dst[node], blane);
        if (RELU) t = fmaxf(t, 0.f);
        outx[node * 64 + lane] = t;
    }
}

// Streaming 64-row GEMM tile (r7-exact body): W in LDS once, X direct from global.
template <int K>
__global__ __launch_bounds__(256, 5) void gemm_tile(const float* __restrict__ in,
                                                    const float* __restrict__ W,
                                                    float* __restrict__ out, int n) {
    __shared__ float Ws[K * 64];
    const int tid = threadIdx.x;
    for (int i = tid; i < K * 16; i += 256) ((float4*)Ws)[i] = ((const float4*)W)[i];
    __syncthreads();  // the only barrier in the kernel

    const int tr = tid >> 4, tc = tid & 15;
    const int row0 = blockIdx.x * 64 + tr * 4;
    const float* xr0 = in + (size_t)min(row0 + 0, n - 1) * K;
    const float* xr1 = in + (size_t)min(row0 + 1, n - 1) * K;
    const float* xr2 = in + (size_t)min(row0 + 2, n - 1) * K;
    const float* xr3 = in + (size_t)min(row0 + 3, n - 1) * K;

    float4 acc0 = {0, 0, 0, 0}, acc1 = {0, 0, 0, 0}, acc2 = {0, 0, 0, 0}, acc3 = {0, 0, 0, 0};
#pragma unroll 4
    for (int k4 = 0; k4 < K / 4; ++k4) {
        const int kb = k4 * 4;
        float4 xv0 = *(const float4*)&xr0[kb];
        float4 xv1 = *(const float4*)&xr1[kb];
        float4 xv2 = *(const float4*)&xr2[kb];
        float4 xv3 = *(const float4*)&xr3[kb];
        const float* wb = &Ws[kb * 64 + tc * 4];
        float4 wk;
        wk = *(const float4*)(wb);
        row_fma(acc0, xv0.x, wk); row_fma(acc1, xv1.x, wk); row_fma(acc2, xv2.x, wk); row_fma(acc3, xv3.x, wk);
        wk = *(const float4*)(wb + 64);
        row_fma(acc0, xv0.y, wk); row_fma(acc1, xv1.y, wk); row_fma(acc2, xv2.y, wk); row_fma(acc3, xv3.y, wk);
        wk = *(const float4*)(wb + 128);
        row_fma(acc0, xv0.z, wk); row_fma(acc1, xv1.z, wk); row_fma(acc2, xv2.z, wk); row_fma(acc3, xv3.z, wk);
        wk = *(const float4*)(wb + 192);
        row_fma(acc0, xv0.w, wk); row_fma(acc1, xv1.w, wk); row_fma(acc2, xv2.w, wk); row_fma(acc3, xv3.w, wk);
    }

#pragma unroll
    for (int i = 0; i < 4; ++i) {
        int row = row0 + i;
        if (row < n) {
            float4 o = (i == 0) ? acc0 : (i == 1) ? acc1 : (i == 2) ? acc2 : acc3;
            *(float4*)&out[row * 64 + tc * 4] = o;
        }
    }
}

#define ZST 76  // Zs row stride

// 32 pairs per block (grid = 6250): halved LDS -> more resident blocks,
// single 16-load gather round per wave, 2x4 register tile GEMMs.
__global__ __launch_bounds__(256) void mlp_tile(const float* __restrict__ hfin,
                                                const float* __restrict__ P0,
                                                const float* __restrict__ pb0,
                                                const float* __restrict__ P1,
                                                const float* __restrict__ pb1,
                                                const float* __restrict__ P2,
                                                const float* __restrict__ pb2,
                                                const int* __restrict__ pos_src,
                                                const int* __restrict__ pos_dst,
                                                const int* __restrict__ neg_src,
                                                const int* __restrict__ neg_dst,
                                                float* __restrict__ out, int P) {
    __shared__ float Zs[32][ZST];
    __shared__ float pb0s[64], pb1s[64], P2s[64];
    __shared__ int pas[32], pbs[32];
    const int tid = threadIdx.x;
    const int base = blockIdx.x << 5;  // 32 pairs per block
    if (tid < 64) {
        pb0s[tid] = pb0[tid];
        pb1s[tid] = pb1[tid];
        P2s[tid] = P2[tid];
        if (tid < 32) {
            int p = base + tid;
            pas[tid] = (p < P) ? pos_src[p] : neg_src[p - P];
            pbs[tid] = (p < P) ? pos_dst[p] : neg_dst[p - P];
        }
    }
    const float pb2v = pb2[0];
    const int lane = tid & 63, w = tid >> 6;
    const int tr = tid >> 4, tc = tid & 15;  // tr in [0,16): 2 rows each
    __syncthreads();

    // gather + product: wave w owns pairs [w*8, w*8+8) — all 16 loads in flight
    {
        const int p0 = w * 8;
        int a0 = pas[p0 + 0], b0 = pbs[p0 + 0];
        int a1 = pas[p0 + 1], b1 = pbs[p0 + 1];
        int a2 = pas[p0 + 2], b2 = pbs[p0 + 2];
        int a3 = pas[p0 + 3], b3 = pbs[p0 + 3];
        int a4 = pas[p0 + 4], b4 = pbs[p0 + 4];
        int a5 = pas[p0 + 5], b5 = pbs[p0 + 5];
        int a6 = pas[p0 + 6], b6 = pbs[p0 + 6];
        int a7 = pas[p0 + 7], b7 = pbs[p0 + 7];
        float ha0 = hfin[a0 * 64 + lane], hb0 = hfin[b0 * 64 + lane];
        float ha1 = hfin[a1 * 64 + lane], hb1 = hfin[b1 * 64 + lane];
        float ha2 = hfin[a2 * 64 + lane], hb2 = hfin[b2 * 64 + lane];
        float ha3 = hfin[a3 * 64 + lane], hb3 = hfin[b3 * 64 + lane];
        float ha4 = hfin[a4 * 64 + lane], hb4 = hfin[b4 * 64 + lane];
        float ha5 = hfin[a5 * 64 + lane], hb5 = hfin[b5 * 64 + lane];
        float ha6 = hfin[a6 * 64 + lane], hb6 = hfin[b6 * 64 + lane];
        float ha7 = hfin[a7 * 64 + lane], hb7 = hfin[b7 * 64 + lane];
        Zs[p0 + 0][lane] = ha0 * hb0;
        Zs[p0 + 1][lane] = ha1 * hb1;
        Zs[p0 + 2][lane] = ha2 * hb2;
        Zs[p0 + 3][lane] = ha3 * hb3;
        Zs[p0 + 4][lane] = ha4 * hb4;
        Zs[p0 + 5][lane] = ha5 * hb5;
        Zs[p0 + 6][lane] = ha6 * hb6;
        Zs[p0 + 7][lane] = ha7 * hb7;
    }
    __syncthreads();

    // layer 0: Z1 = relu(Z @ P0 + pb0)   (2 rows x 4 cols per thread)
    float4 acc0, acc1;
    {
        float4 binit = *(const float4*)&pb0s[tc * 4];
        acc0 = binit; acc1 = binit;
    }
#pragma unroll 4
    for (int k4 = 0; k4 < 16; ++k4) {
        const int kb = k4 * 4;
        float4 xv0 = *(const float4*)&Zs[tr * 2 + 0][kb];
        float4 xv1 = *(const float4*)&Zs[tr * 2 + 1][kb];
        const float* wb = &P0[kb * 64 + tc * 4];
        float4 wk;
        wk = *(const float4*)(wb);
        row_fma(acc0, xv0.x, wk); row_fma(acc1, xv1.x, wk);
        wk = *(const float4*)(wb + 64);
        row_fma(acc0, xv0.y, wk); row_fma(acc1, xv1.y, wk);
        wk = *(const float4*)(wb + 128);
        row_fma(acc0, xv0.z, wk); row_fma(acc1, xv1.z, wk);
        wk = *(const float4*)(wb + 192);
        row_fma(acc0, xv0.w, wk); row_fma(acc1, xv1.w, wk);
    }
    __syncthreads();
    {
        float4 o = acc0;
        o.x = fmaxf(o.x, 0.f); o.y = fmaxf(o.y, 0.f); o.z = fmaxf(o.z, 0.f); o.w = fmaxf(o.w, 0.f);
        *(float4*)&Zs[tr * 2 + 0][tc * 4] = o;
        o = acc1;
        o.x = fmaxf(o.x, 0.f); o.y = fmaxf(o.y, 0.f); o.z = fmaxf(o.z, 0.f); o.w = fmaxf(o.w, 0.f);
        *(float4*)&Zs[tr * 2 + 1][tc * 4] = o;
    }
    __syncthreads();

    // layer 1: Z2 = relu(Z1 @ P1 + pb1)
    {
        float4 binit = *(const float4*)&pb1s[tc * 4];
        acc0 = binit; acc1 = binit;
    }
#pragma unroll 4
    for (int k4 = 0; k4 < 16; ++k4) {
        const int kb = k4 * 4;
        float4 xv0 = *(const float4*)&Zs[tr * 2 + 0][kb];
        float4 xv1 = *(const float4*)&Zs[tr * 2 + 1][kb];
        const float* wb = &P1[kb * 64 + tc * 4];
        float4 wk;
        wk = *(const float4*)(wb);
        row_fma(acc0, xv0.x, wk); row_fma(acc1, xv1.x, wk);
        wk = *(const float4*)(wb + 64);
        row_fma(acc0, xv0.y, wk); row_fma(acc1, xv1.y, wk);
        wk = *(const float4*)(wb + 128);
        row_fma(acc0, xv0.z, wk); row_fma(acc1, xv1.z, wk);
        wk = *(const float4*)(wb + 192);
        row_fma(acc0, xv0.w, wk); row_fma(acc1, xv1.w, wk);
    }
    __syncthreads();
    {
        float4 o = acc0;
        o.x = fmaxf(o.x, 0.f); o.y = fmaxf(o.y, 0.f); o.z = fmaxf(o.z, 0.f); o.w = fmaxf(o.w, 0.f);
        *(float4*)&Zs[tr * 2 + 0][tc * 4] = o;
        o = acc1;
        o.x = fmaxf(o.x, 0.f); o.y = fmaxf(o.y, 0.f); o.z = fmaxf(o.z, 0.f); o.w = fmaxf(o.w, 0.f);
        *(float4*)&Zs[tr * 2 + 1][tc * 4] = o;
    }
    __syncthreads();

    // final GEMV: out[p] = Z2[p] . P2 + pb2   (8 lanes per pair, 8 k each)
    {
        int p = tid >> 3, kq = tid & 7;
        float s = 0.f;
#pragma unroll
        for (int i = 0; i < 8; ++i) s = fmaf(Zs[p][kq * 8 + i], P2s[kq * 8 + i], s);
        s += __shfl_xor(s, 1, 64);
        s += __shfl_xor(s, 2, 64);
        s += __shfl_xor(s, 4, 64);
        if (kq == 0) out[base + p] = s + pb2v;
    }
}

extern "C" void kernel_launch(void* const* d_in, const int* in_sizes, int n_in,
                              void* d_out, int out_size, void* d_ws, size_t ws_size,
                              hipStream_t stream) {
    const float* x     = (const float*)d_in[0];
    const float* ew    = (const float*)d_in[1];  // (3, E)
    const int* src     = (const int*)d_in[2];
    const int* dst     = (const int*)d_in[3];
    const int* pos_src = (const int*)d_in[4];
    const int* pos_dst = (const int*)d_in[5];
    const int* neg_src = (const int*)d_in[6];
    const int* neg_dst = (const int*)d_in[7];
    const float* W0    = (const float*)d_in[8];
    const float* b0    = (const float*)d_in[9];
    const float* W1    = (const float*)d_in[10];
    const float* b1    = (const float*)d_in[11];
    const float* W2    = (const float*)d_in[12];
    const float* b2    = (const float*)d_in[13];
    const float* P0    = (const float*)d_in[14];
    const float* pb0   = (const float*)d_in[15];
    const float* P1    = (const float*)d_in[16];
    const float* pb1   = (const float*)d_in[17];
    const float* P2    = (const float*)d_in[18];
    const float* pb2   = (const float*)d_in[19];
    float* out = (float*)d_out;

    float* ws = (float*)d_ws;
    float* norm_src = ws;                     // N
    float* norm_dst = ws + 100000;            // N
    int* cursor     = (int*)(ws + 200000);    // N
    int* deg_in     = (int*)(ws + 300000);    // N
    int* row_ptr    = (int*)(ws + 400000);    // N+1
    float4* cedge   = (float4*)(ws + 500004); // E
    float* hw       = ws + 4500004;           // N*64
    float* agg      = ws + 10900004;          // N*64

    // pre-layer0 scratch inside hw region (not yet live)
    int* repl      = (int*)hw;            // 16*NN ints
    int* tmp_excl  = (int*)hw + 16 * NN;  // NN
    int* blocksums = (int*)hw + 17 * NN;  // SCAN_NB

    hipMemsetAsync(repl, 0, 16 * NN * sizeof(int), stream);
    deg_kernel<<<(NE / 4 + 255) / 256, 256, 0, stream>>>((const int4*)src, (const int4*)dst,
                                                         repl, NE / 4);
    reduce_norm_kernel<<<(NN + 255) / 256, 256, 0, stream>>>(repl, norm_src, norm_dst, deg_in, NN);
    scan_block<<<SCAN_NB, 1024, 0, stream>>>(deg_in, tmp_excl, blocksums, NN);
    scan_sums<<<1, 128, 0, stream>>>(blocksums, SCAN_NB);
    scan_apply<<<SCAN_NB, 1024, 0, stream>>>(tmp_excl, blocksums, row_ptr, cursor, NN);
    csr_fill<<<2048, 256, 0, stream>>>(src, dst, ew, norm_src, cursor, cedge, NE);

    const int NT = (NN + 63) / 64;  // 1563 tiles

    // layer 0
    gemm_tile<128><<<NT, 256, 0, stream>>>(x, W0, hw, NN);
    aggregate<0, true><<<4096, 256, 0, stream>>>(hw, cedge, row_ptr, norm_dst, b0, agg, NN);
    // layer 1
    gemm_tile<64><<<NT, 256, 0, stream>>>(agg, W1, hw, NN);
    aggregate<1, true><<<4096, 256, 0, stream>>>(hw, cedge, row_ptr, norm_dst, b1, agg, NN);
    // layer 2 (final, no relu)
    gemm_tile<64><<<NT, 256, 0, stream>>>(agg, W2, hw, NN);
    aggregate<2, false><<<4096, 256, 0, stream>>>(hw, cedge, row_ptr, norm_dst, b2, agg, NN);

    // MLP over pos & neg pairs (32 pairs per block)
    mlp_tile<<<(2 * NP) / 32, 256, 0, stream>>>(agg, P0, pb0, P1, pb1, P2, pb2,
                                                pos_src, pos_dst, neg_src, neg_dst, out, NP);
}

// Round 13
// 475.750 us; speedup vs baseline: 2.3861x; 1.0830x over previous
//
#include <hip/hip_runtime.h>

// GCN link predictor, fp32 — round 13: mlp gather rebuilt.
//  r12 lesson: 32-pair mlp raised occupancy (75%) but VGPR fell to 32 ->
//  compiler serialized the 16 gather loads (BW 606 GB/s, 110us). For
//  latency-bound gathers, outstanding-loads beat occupancy.
//  New mlp: 64 pairs/block, float4-coalesced gather (16 lanes per row,
//  16B/lane), 8 float4 loads in flight per lane via fully-unrolled reg array.
//
// ws layout (float units):
//   0        norm_src [N]
//   100000   norm_dst [N]
//   200000   cursor (int) [N]
//   300000   deg_in (int) [N]
//   400000   row_ptr (int) [N+1]
//   500004   cedge (float4) [E]        (src, ns*w_l0, ns*w_l1, ns*w_l2)
//   4500004  hw   [N*64]  (pre-layer0: deg replicas 16N ints + scan scratch)
//   10900004 agg  [N*64]
// total 17300004 floats = 69.2 MB

#define NN 100000
#define NE 1000000
#define NP 100000
#define SCAN_NB 98

__device__ __forceinline__ void row_fma(float4& acc, float xv, const float4& wv) {
    acc.x = fmaf(xv, wv.x, acc.x);
    acc.y = fmaf(xv, wv.y, acc.y);
    acc.z = fmaf(xv, wv.z, acc.z);
    acc.w = fmaf(xv, wv.w, acc.w);
}

// per-XCD replicated degree count: atomics stay in the local (XCD) L2.
__global__ void deg_kernel(const int4* __restrict__ src4, const int4* __restrict__ dst4,
                           int* __restrict__ repl, int E4) {
    int xcc;
    asm volatile("s_getreg_b32 %0, hwreg(HW_REG_XCC_ID)" : "=s"(xcc));
    xcc &= 7;
    int* dout = repl + xcc * NN;
    int* din  = repl + (8 + xcc) * NN;
    int tid = blockIdx.x * blockDim.x + threadIdx.x;
    if (tid < E4) {
        int4 s = src4[tid], d = dst4[tid];
        __hip_atomic_fetch_add(&dout[s.x], 1, __ATOMIC_RELAXED, __HIP_MEMORY_SCOPE_WORKGROUP);
        __hip_atomic_fetch_add(&dout[s.y], 1, __ATOMIC_RELAXED, __HIP_MEMORY_SCOPE_WORKGROUP);
        __hip_atomic_fetch_add(&dout[s.z], 1, __ATOMIC_RELAXED, __HIP_MEMORY_SCOPE_WORKGROUP);
        __hip_atomic_fetch_add(&dout[s.w], 1, __ATOMIC_RELAXED, __HIP_MEMORY_SCOPE_WORKGROUP);
        __hip_atomic_fetch_add(&din[d.x], 1, __ATOMIC_RELAXED, __HIP_MEMORY_SCOPE_WORKGROUP);
        __hip_atomic_fetch_add(&din[d.y], 1, __ATOMIC_RELAXED, __HIP_MEMORY_SCOPE_WORKGROUP);
        __hip_atomic_fetch_add(&din[d.z], 1, __ATOMIC_RELAXED, __HIP_MEMORY_SCOPE_WORKGROUP);
        __hip_atomic_fetch_add(&din[d.w], 1, __ATOMIC_RELAXED, __HIP_MEMORY_SCOPE_WORKGROUP);
    }
}

__global__ void reduce_norm_kernel(const int* __restrict__ repl, float* __restrict__ norm_src,
                                   float* __restrict__ norm_dst, int* __restrict__ deg_in, int n) {
    int i = blockIdx.x * blockDim.x + threadIdx.x;
    if (i < n) {
        int so = 0, si = 0;
#pragma unroll
        for (int x = 0; x < 8; ++x) {
            so += repl[x * NN + i];
            si += repl[(8 + x) * NN + i];
        }
        norm_src[i] = rsqrtf(fmaxf((float)so, 1.0f));
        norm_dst[i] = rsqrtf(fmaxf((float)si, 1.0f));
        deg_in[i] = si;
    }
}

__global__ __launch_bounds__(1024) void scan_block(const int* __restrict__ deg,
                                                   int* __restrict__ tmp_excl,
                                                   int* __restrict__ blocksums, int n) {
    __shared__ int wsums[16];
    const int i = blockIdx.x * 1024 + threadIdx.x;
    const int lane = threadIdx.x & 63, w = threadIdx.x >> 6;
    int v = (i < n) ? deg[i] : 0;
    int s = v;
#pragma unroll
    for (int off = 1; off < 64; off <<= 1) {
        int u = __shfl_up(s, off, 64);
        if (lane >= off) s += u;
    }
    if (lane == 63) wsums[w] = s;
    __syncthreads();
    if (w == 0) {
        int wv = (lane < 16) ? wsums[lane] : 0;
#pragma unroll
        for (int off = 1; off < 16; off <<= 1) {
            int u = __shfl_up(wv, off, 64);
            if (lane >= off) wv += u;
        }
        if (lane < 16) wsums[lane] = wv;
    }
    __syncthreads();
    int excl = s - v + (w > 0 ? wsums[w - 1] : 0);
    if (i < n) tmp_excl[i] = excl;
    if (threadIdx.x == 1023) blocksums[blockIdx.x] = excl + v;
}

__global__ void scan_sums(int* __restrict__ bs, int nb) {
    __shared__ int wtot[2];
    const int t = threadIdx.x;  // 128 threads
    const int lane = t & 63, w = t >> 6;
    int v = (t < nb) ? bs[t] : 0;
    int s = v;
#pragma unroll
    for (int off = 1; off < 64; off <<= 1) {
        int u = __shfl_up(s, off, 64);
        if (lane >= off) s += u;
    }
    if (lane == 63) wtot[w] = s;
    __syncthreads();
    int excl = s - v + (w == 1 ? wtot[0] : 0);
    if (t < nb) bs[t] = excl;
}

__global__ __launch_bounds__(1024) void scan_apply(const int* __restrict__ tmp_excl,
                                                   const int* __restrict__ bs,
                                                   int* __restrict__ row_ptr,
                                                   int* __restrict__ cursor, int n) {
    const int i = blockIdx.x * 1024 + threadIdx.x;
    if (i < n) {
        int r = tmp_excl[i] + bs[blockIdx.x];
        row_ptr[i] = r;
        cursor[i] = r;
    }
    if (i == 0) row_ptr[n] = NE;
}

// pack each edge into its dst row; fold norm_src[src] into all 3 layer weights.
__global__ void csr_fill(const int* __restrict__ src, const int* __restrict__ dst,
                         const float* __restrict__ ew, const float* __restrict__ norm_src,
                         int* __restrict__ cursor, float4* __restrict__ cedge, int E) {
    int tid = blockIdx.x * blockDim.x + threadIdx.x;
    int stride = gridDim.x * blockDim.x;
    for (int e = tid; e < E; e += stride) {
        int s = src[e];
        int d = dst[e];
        float nsv = norm_src[s];
        int slot = atomicAdd(&cursor[d], 1);
        float4 c;
        c.x = __int_as_float(s);
        c.y = ew[e] * nsv;
        c.z = ew[NE + e] * nsv;
        c.w = ew[2 * NE + e] * nsv;
        cedge[slot] = c;
    }
}

// Pure-gather CSR aggregation, one wave per dst node, 8-deep batched loads.
template <int WSEL, bool RELU>
__global__ __launch_bounds__(256) void aggregate(const float* __restrict__ hw,
                                                 const float4* __restrict__ cedge,
                                                 const int* __restrict__ row_ptr,
                                                 const float* __restrict__ norm_dst,
                                                 const float* __restrict__ bias,
                                                 float* __restrict__ outx, int n) {
    const int lane = threadIdx.x & 63;
    const int gw = (blockIdx.x * blockDim.x + threadIdx.x) >> 6;
    const int nw = (gridDim.x * blockDim.x) >> 6;
    const float blane = bias[lane];
    for (int node = gw; node < n; node += nw) {
        int beg = row_ptr[node], end = row_ptr[node + 1];
        float a0 = 0.f, a1 = 0.f, a2 = 0.f, a3 = 0.f;
        int i = beg;
        for (; i + 7 < end; i += 8) {
            float4 c0 = cedge[i + 0], c1 = cedge[i + 1], c2 = cedge[i + 2], c3 = cedge[i + 3];
            float4 c4 = cedge[i + 4], c5 = cedge[i + 5], c6 = cedge[i + 6], c7 = cedge[i + 7];
            float h0 = hw[__float_as_int(c0.x) * 64 + lane];
            float h1 = hw[__float_as_int(c1.x) * 64 + lane];
            float h2 = hw[__float_as_int(c2.x) * 64 + lane];
            float h3 = hw[__float_as_int(c3.x) * 64 + lane];
            float h4 = hw[__float_as_int(c4.x) * 64 + lane];
            float h5 = hw[__float_as_int(c5.x) * 64 + lane];
            float h6 = hw[__float_as_int(c6.x) * 64 + lane];
            float h7 = hw[__float_as_int(c7.x) * 64 + lane];
            a0 = fmaf(h0, (WSEL == 0) ? c0.y : (WSEL == 1) ? c0.z : c0.w, a0);
            a1 = fmaf(h1, (WSEL == 0) ? c1.y : (WSEL == 1) ? c1.z : c1.w, a1);
            a2 = fmaf(h2, (WSEL == 0) ? c2.y : (WSEL == 1) ? c2.z : c2.w, a2);
            a3 = fmaf(h3, (WSEL == 0) ? c3.y : (WSEL == 1) ? c3.z : c3.w, a3);
            a0 = fmaf(h4, (WSEL == 0) ? c4.y : (WSEL == 1) ? c4.z : c4.w, a0);
            a1 = fmaf(h5, (WSEL == 0) ? c5.y : (WSEL == 1) ? c5.z : c5.w, a1);
            a2 = fmaf(h6, (WSEL == 0) ? c6.y : (WSEL == 1) ? c6.z : c6.w, a2);
            a3 = fmaf(h7, (WSEL == 0) ? c7.y : (WSEL == 1) ? c7.z : c7.w, a3);
        }
        for (; i + 1 < end; i += 2) {
            float4 c0 = cedge[i], c1 = cedge[i + 1];
            float h0 = hw[__float_as_int(c0.x) * 64 + lane];
            float h1 = hw[__float_as_int(c1.x) * 64 + lane];
            a0 = fmaf(h0, (WSEL == 0) ? c0.y : (WSEL == 1) ? c0.z : c0.w, a0);
            a1 = fmaf(h1, (WSEL == 0) ? c1.y : (WSEL == 1) ? c1.z : c1.w, a1);
        }
        if (i < end) {
            float4 c0 = cedge[i];
            float h0 = hw[__float_as_int(c0.x) * 64 + lane];
            a0 = fmaf(h0, (WSEL == 0) ? c0.y : (WSEL == 1) ? c0.z : c0.w, a0);
        }
        float a = (a0 + a1) + (a2 + a3);
        float t = fmaf(a, norm_dst[node], blane);
        if (RELU) t = fmaxf(t, 0.f);
        outx[node * 64 + lane] = t;
    }
}

// Streaming 64-row GEMM tile (r7-exact body): W in LDS once, X direct from global.
template <int K>
__global__ __launch_bounds__(256, 5) void gemm_tile(const float* __restrict__ in,
                                                    const float* __restrict__ W,
                                                    float* __restrict__ out, int n) {
    __shared__ float Ws[K * 64];
    const int tid = threadIdx.x;
    for (int i = tid; i < K * 16; i += 256) ((float4*)Ws)[i] = ((const float4*)W)[i];
    __syncthreads();  // the only barrier in the kernel

    const int tr = tid >> 4, tc = tid & 15;
    const int row0 = blockIdx.x * 64 + tr * 4;
    const float* xr0 = in + (size_t)min(row0 + 0, n - 1) * K;
    const float* xr1 = in + (size_t)min(row0 + 1, n - 1) * K;
    const float* xr2 = in + (size_t)min(row0 + 2, n - 1) * K;
    const float* xr3 = in + (size_t)min(row0 + 3, n - 1) * K;

    float4 acc0 = {0, 0, 0, 0}, acc1 = {0, 0, 0, 0}, acc2 = {0, 0, 0, 0}, acc3 = {0, 0, 0, 0};
#pragma unroll 4
    for (int k4 = 0; k4 < K / 4; ++k4) {
        const int kb = k4 * 4;
        float4 xv0 = *(const float4*)&xr0[kb];
        float4 xv1 = *(const float4*)&xr1[kb];
        float4 xv2 = *(const float4*)&xr2[kb];
        float4 xv3 = *(const float4*)&xr3[kb];
        const float* wb = &Ws[kb * 64 + tc * 4];
        float4 wk;
        wk = *(const float4*)(wb);
        row_fma(acc0, xv0.x, wk); row_fma(acc1, xv1.x, wk); row_fma(acc2, xv2.x, wk); row_fma(acc3, xv3.x, wk);
        wk = *(const float4*)(wb + 64);
        row_fma(acc0, xv0.y, wk); row_fma(acc1, xv1.y, wk); row_fma(acc2, xv2.y, wk); row_fma(acc3, xv3.y, wk);
        wk = *(const float4*)(wb + 128);
        row_fma(acc0, xv0.z, wk); row_fma(acc1, xv1.z, wk); row_fma(acc2, xv2.z, wk); row_fma(acc3, xv3.z, wk);
        wk = *(const float4*)(wb + 192);
        row_fma(acc0, xv0.w, wk); row_fma(acc1, xv1.w, wk); row_fma(acc2, xv2.w, wk); row_fma(acc3, xv3.w, wk);
    }

#pragma unroll
    for (int i = 0; i < 4; ++i) {
        int row = row0 + i;
        if (row < n) {
            float4 o = (i == 0) ? acc0 : (i == 1) ? acc1 : (i == 2) ? acc2 : acc3;
            *(float4*)&out[row * 64 + tc * 4] = o;
        }
    }
}

#define ZST 76  // Zs row stride

// 64 pairs per block (grid = 3125). Gather is float4-coalesced: 16 lanes per
// row (16B/lane), wave owns 16 pairs, 8 float4 loads in flight per lane.
__global__ __launch_bounds__(256) void mlp_tile(const float* __restrict__ hfin,
                                                const float* __restrict__ P0,
                                                const float* __restrict__ pb0,
                                                const float* __restrict__ P1,
                                                const float* __restrict__ pb1,
                                                const float* __restrict__ P2,
                                                const float* __restrict__ pb2,
                                                const int* __restrict__ pos_src,
                                                const int* __restrict__ pos_dst,
                                                const int* __restrict__ neg_src,
                                                const int* __restrict__ neg_dst,
                                                float* __restrict__ out, int P) {
    __shared__ float Zs[64][ZST];
    __shared__ float pb0s[64], pb1s[64], P2s[64];
    __shared__ int pas[64], pbs[64];
    const int tid = threadIdx.x;
    const int base = blockIdx.x << 6;
    if (tid < 64) {
        pb0s[tid] = pb0[tid];
        pb1s[tid] = pb1[tid];
        P2s[tid] = P2[tid];
        int p = base + tid;
        pas[tid] = (p < P) ? pos_src[p] : neg_src[p - P];
        pbs[tid] = (p < P) ? pos_dst[p] : neg_dst[p - P];
    }
    const float pb2v = pb2[0];
    const int lane = tid & 63, w = tid >> 6;
    const int tr = tid >> 4, tc = tid & 15;
    __syncthreads();

    // gather + product, float4-coalesced: wave w owns pairs [w*16, w*16+16).
    // 16 lanes cooperate per row; lane handles pair (r*4 + lane>>4), cols (lane&15)*4.
    {
        const int sub = lane >> 4;       // 0..3: which pair within the quad
        const int c4 = (lane & 15) * 4;  // feature column base
        float4 ha[4], hb[4];
#pragma unroll
        for (int r = 0; r < 4; ++r) {
            const int pi = w * 16 + r * 4 + sub;
            ha[r] = *(const float4*)&hfin[pas[pi] * 64 + c4];
            hb[r] = *(const float4*)&hfin[pbs[pi] * 64 + c4];
        }
#pragma unroll
        for (int r = 0; r < 4; ++r) {
            const int pi = w * 16 + r * 4 + sub;
            float4 z;
            z.x = ha[r].x * hb[r].x;
            z.y = ha[r].y * hb[r].y;
            z.z = ha[r].z * hb[r].z;
            z.w = ha[r].w * hb[r].w;
            *(float4*)&Zs[pi][c4] = z;
        }
    }
    __syncthreads();

    // layer 0: Z1 = relu(Z @ P0 + pb0)
    float4 acc0, acc1, acc2, acc3;
    {
        float4 binit = *(const float4*)&pb0s[tc * 4];
        acc0 = binit; acc1 = binit; acc2 = binit; acc3 = binit;
    }
#pragma unroll 4
    for (int k4 = 0; k4 < 16; ++k4) {
        const int kb = k4 * 4;
        float4 xv0 = *(const float4*)&Zs[tr * 4 + 0][kb];
        float4 xv1 = *(const float4*)&Zs[tr * 4 + 1][kb];
        float4 xv2 = *(const float4*)&Zs[tr * 4 + 2][kb];
        float4 xv3 = *(const float4*)&Zs[tr * 4 + 3][kb];
        const float* wb = &P0[kb * 64 + tc * 4];
        float4 wk;
        wk = *(const float4*)(wb);
        row_fma(acc0, xv0.x, wk); row_fma(acc1, xv1.x, wk); row_fma(acc2, xv2.x, wk); row_fma(acc3, xv3.x, wk);
        wk = *(const float4*)(wb + 64);
        row_fma(acc0, xv0.y, wk); row_fma(acc1, xv1.y, wk); row_fma(acc2, xv2.y, wk); row_fma(acc3, xv3.y, wk);
        wk = *(const float4*)(wb + 128);
        row_fma(acc0, xv0.z, wk); row_fma(acc1, xv1.z, wk); row_fma(acc2, xv2.z, wk); row_fma(acc3, xv3.z, wk);
        wk = *(const float4*)(wb + 192);
        row_fma(acc0, xv0.w, wk); row_fma(acc1, xv1.w, wk); row_fma(acc2, xv2.w, wk); row_fma(acc3, xv3.w, wk);
    }
    __syncthreads();
#pragma unroll
    for (int i = 0; i < 4; ++i) {
        float4 o = (i == 0) ? acc0 : (i == 1) ? acc1 : (i == 2) ? acc2 : acc3;
        o.x = fmaxf(o.x, 0.f); o.y = fmaxf(o.y, 0.f); o.z = fmaxf(o.z, 0.f); o.w = fmaxf(o.w, 0.f);
        *(float4*)&Zs[tr * 4 + i][tc * 4] = o;
    }
    __syncthreads();

    // layer 1: Z2 = relu(Z1 @ P1 + pb1)
    {
        float4 binit = *(const float4*)&pb1s[tc * 4];
        acc0 = binit; acc1 = binit; acc2 = binit; acc3 = binit;
    }
#pragma unroll 4
    for (int k4 = 0; k4 < 16; ++k4) {
        const int kb = k4 * 4;
        float4 xv0 = *(const float4*)&Zs[tr * 4 + 0][kb];
        float4 xv1 = *(const float4*)&Zs[tr * 4 + 1][kb];
        float4 xv2 = *(const float4*)&Zs[tr * 4 + 2][kb];
        float4 xv3 = *(const float4*)&Zs[tr * 4 + 3][kb];
        const float* wb = &P1[kb * 64 + tc * 4];
        float4 wk;
        wk = *(const float4*)(wb);
        row_fma(acc0, xv0.x, wk); row_fma(acc1, xv1.x, wk); row_fma(acc2, xv2.x, wk); row_fma(acc3, xv3.x, wk);
        wk = *(const float4*)(wb + 64);
        row_fma(acc0, xv0.y, wk); row_fma(acc1, xv1.y, wk); row_fma(acc2, xv2.y, wk); row_fma(acc3, xv3.y, wk);
        wk = *(const float4*)(wb + 128);
        row_fma(acc0, xv0.z, wk); row_fma(acc1, xv1.z, wk); row_fma(acc2, xv2.z, wk); row_fma(acc3, xv3.z, wk);
        wk = *(const float4*)(wb + 192);
        row_fma(acc0, xv0.w, wk); row_fma(acc1, xv1.w, wk); row_fma(acc2, xv2.w, wk); row_fma(acc3, xv3.w, wk);
    }
    __syncthreads();
#pragma unroll
    for (int i = 0; i < 4; ++i) {
        float4 o = (i == 0) ? acc0 : (i == 1) ? acc1 : (i == 2) ? acc2 : acc3;
        o.x = fmaxf(o.x, 0.f); o.y = fmaxf(o.y, 0.f); o.z = fmaxf(o.z, 0.f); o.w = fmaxf(o.w, 0.f);
        *(float4*)&Zs[tr * 4 + i][tc * 4] = o;
    }
    __syncthreads();

    // final GEMV: out[p] = Z2[p] . P2 + pb2   (4 lanes per pair, 16 k each)
    {
        int p = tid >> 2, kq = tid & 3;
        float s = 0.f;
#pragma unroll
        for (int i = 0; i < 16; ++i) s = fmaf(Zs[p][kq * 16 + i], P2s[kq * 16 + i], s);
        s += __shfl_xor(s, 1, 64);
        s += __shfl_xor(s, 2, 64);
        if (kq == 0) out[base + p] = s + pb2v;
    }
}

extern "C" void kernel_launch(void* const* d_in, const int* in_sizes, int n_in,
                              void* d_out, int out_size, void* d_ws, size_t ws_size,
                              hipStream_t stream) {
    const float* x     = (const float*)d_in[0];
    const float* ew    = (const float*)d_in[1];  // (3, E)
    const int* src     = (const int*)d_in[2];
    const int* dst     = (const int*)d_in[3];
    const int* pos_src = (const int*)d_in[4];
    const int* pos_dst = (const int*)d_in[5];
    const int* neg_src = (const int*)d_in[6];
    const int* neg_dst = (const int*)d_in[7];
    const float* W0    = (const float*)d_in[8];
    const float* b0    = (const float*)d_in[9];
    const float* W1    = (const float*)d_in[10];
    const float* b1    = (const float*)d_in[11];
    const float* W2    = (const float*)d_in[12];
    const float* b2    = (const float*)d_in[13];
    const float* P0    = (const float*)d_in[14];
    const float* pb0   = (const float*)d_in[15];
    const float* P1    = (const float*)d_in[16];
    const float* pb1   = (const float*)d_in[17];
    const float* P2    = (const float*)d_in[18];
    const float* pb2   = (const float*)d_in[19];
    float* out = (float*)d_out;

    float* ws = (float*)d_ws;
    float* norm_src = ws;                     // N
    float* norm_dst = ws + 100000;            // N
    int* cursor     = (int*)(ws + 200000);    // N
    int* deg_in     = (int*)(ws + 300000);    // N
    int* row_ptr    = (int*)(ws + 400000);    // N+1
    float4* cedge   = (float4*)(ws + 500004); // E
    float* hw       = ws + 4500004;           // N*64
    float* agg      = ws + 10900004;          // N*64

    // pre-layer0 scratch inside hw region (not yet live)
    int* repl      = (int*)hw;            // 16*NN ints
    int* tmp_excl  = (int*)hw + 16 * NN;  // NN
    int* blocksums = (int*)hw + 17 * NN;  // SCAN_NB

    hipMemsetAsync(repl, 0, 16 * NN * sizeof(int), stream);
    deg_kernel<<<(NE / 4 + 255) / 256, 256, 0, stream>>>((const int4*)src, (const int4*)dst,
                                                         repl, NE / 4);
    reduce_norm_kernel<<<(NN + 255) / 256, 256, 0, stream>>>(repl, norm_src, norm_dst, deg_in, NN);
    scan_block<<<SCAN_NB, 1024, 0, stream>>>(deg_in, tmp_excl, blocksums, NN);
    scan_sums<<<1, 128, 0, stream>>>(blocksums, SCAN_NB);
    scan_apply<<<SCAN_NB, 1024, 0, stream>>>(tmp_excl, blocksums, row_ptr, cursor, NN);
    csr_fill<<<2048, 256, 0, stream>>>(src, dst, ew, norm_src, cursor, cedge, NE);

    const int NT = (NN + 63) / 64;  // 1563 tiles

    // layer 0
    gemm_tile<128><<<NT, 256, 0, stream>>>(x, W0, hw, NN);
    aggregate<0, true><<<4096, 256, 0, stream>>>(hw, cedge, row_ptr, norm_dst, b0, agg, NN);
    // layer 1
    gemm_tile<64><<<NT, 256, 0, stream>>>(agg, W1, hw, NN);
    aggregate<1, true><<<4096, 256, 0, stream>>>(hw, cedge, row_ptr, norm_dst, b1, agg, NN);
    // layer 2 (final, no relu)
    gemm_tile<64><<<NT, 256, 0, stream>>>(agg, W2, hw, NN);
    aggregate<2, false><<<4096, 256, 0, stream>>>(hw, cedge, row_ptr, norm_dst, b2, agg, NN);

    // MLP over pos & neg pairs (64 pairs per block)
    mlp_tile<<<(2 * NP) / 64, 256, 0, stream>>>(agg, P0, pb0, P1, pb1, P2, pb2,
                                                pos_src, pos_dst, neg_src, neg_dst, out, NP);
}

// Round 14
// 450.126 us; speedup vs baseline: 2.5220x; 1.0569x over previous
//
#include <hip/hip_runtime.h>

// GCN link predictor, fp32 — round 14: pipeline overlap via kernel fusion.
//  The stream is serial, but gemm0 (x@W0) is independent of the CSR preamble.
//  Fuse csr_fill + gemm0 into ONE dispatch (block-range split): saves ~40us of
//  serial latency-bound time. All other kernels byte-identical to r13 (475us).
//
// ws layout (float units):
//   0        norm_src [N]
//   100000   norm_dst [N]
//   200000   cursor (int) [N]
//   300000   deg_in (int) [N]
//   400000   row_ptr (int) [N+1]
//   500004   cedge (float4) [E]        (src, ns*w_l0, ns*w_l1, ns*w_l2)
//   4500004  hw   [N*64]  (pre-layer0: deg replicas 16N ints + scan scratch)
//   10900004 agg  [N*64]
// total 17300004 floats = 69.2 MB

#define NN 100000
#define NE 1000000
#define NP 100000
#define SCAN_NB 98
#define NT 1563  // gemm tiles for N=100000, 64 rows each
#define CSRB 2048

__device__ __forceinline__ void row_fma(float4& acc, float xv, const float4& wv) {
    acc.x = fmaf(xv, wv.x, acc.x);
    acc.y = fmaf(xv, wv.y, acc.y);
    acc.z = fmaf(xv, wv.z, acc.z);
    acc.w = fmaf(xv, wv.w, acc.w);
}

// per-XCD replicated degree count: atomics stay in the local (XCD) L2.
__global__ void deg_kernel(const int4* __restrict__ src4, const int4* __restrict__ dst4,
                           int* __restrict__ repl, int E4) {
    int xcc;
    asm volatile("s_getreg_b32 %0, hwreg(HW_REG_XCC_ID)" : "=s"(xcc));
    xcc &= 7;
    int* dout = repl + xcc * NN;
    int* din  = repl + (8 + xcc) * NN;
    int tid = blockIdx.x * blockDim.x + threadIdx.x;
    if (tid < E4) {
        int4 s = src4[tid], d = dst4[tid];
        __hip_atomic_fetch_add(&dout[s.x], 1, __ATOMIC_RELAXED, __HIP_MEMORY_SCOPE_WORKGROUP);
        __hip_atomic_fetch_add(&dout[s.y], 1, __ATOMIC_RELAXED, __HIP_MEMORY_SCOPE_WORKGROUP);
        __hip_atomic_fetch_add(&dout[s.z], 1, __ATOMIC_RELAXED, __HIP_MEMORY_SCOPE_WORKGROUP);
        __hip_atomic_fetch_add(&dout[s.w], 1, __ATOMIC_RELAXED, __HIP_MEMORY_SCOPE_WORKGROUP);
        __hip_atomic_fetch_add(&din[d.x], 1, __ATOMIC_RELAXED, __HIP_MEMORY_SCOPE_WORKGROUP);
        __hip_atomic_fetch_add(&din[d.y], 1, __ATOMIC_RELAXED, __HIP_MEMORY_SCOPE_WORKGROUP);
        __hip_atomic_fetch_add(&din[d.z], 1, __ATOMIC_RELAXED, __HIP_MEMORY_SCOPE_WORKGROUP);
        __hip_atomic_fetch_add(&din[d.w], 1, __ATOMIC_RELAXED, __HIP_MEMORY_SCOPE_WORKGROUP);
    }
}

__global__ void reduce_norm_kernel(const int* __restrict__ repl, float* __restrict__ norm_src,
                                   float* __restrict__ norm_dst, int* __restrict__ deg_in, int n) {
    int i = blockIdx.x * blockDim.x + threadIdx.x;
    if (i < n) {
        int so = 0, si = 0;
#pragma unroll
        for (int x = 0; x < 8; ++x) {
            so += repl[x * NN + i];
            si += repl[(8 + x) * NN + i];
        }
        norm_src[i] = rsqrtf(fmaxf((float)so, 1.0f));
        norm_dst[i] = rsqrtf(fmaxf((float)si, 1.0f));
        deg_in[i] = si;
    }
}

__global__ __launch_bounds__(1024) void scan_block(const int* __restrict__ deg,
                                                   int* __restrict__ tmp_excl,
                                                   int* __restrict__ blocksums, int n) {
    __shared__ int wsums[16];
    const int i = blockIdx.x * 1024 + threadIdx.x;
    const int lane = threadIdx.x & 63, w = threadIdx.x >> 6;
    int v = (i < n) ? deg[i] : 0;
    int s = v;
#pragma unroll
    for (int off = 1; off < 64; off <<= 1) {
        int u = __shfl_up(s, off, 64);
        if (lane >= off) s += u;
    }
    if (lane == 63) wsums[w] = s;
    __syncthreads();
    if (w == 0) {
        int wv = (lane < 16) ? wsums[lane] : 0;
#pragma unroll
        for (int off = 1; off < 16; off <<= 1) {
            int u = __shfl_up(wv, off, 64);
            if (lane >= off) wv += u;
        }
        if (lane < 16) wsums[lane] = wv;
    }
    __syncthreads();
    int excl = s - v + (w > 0 ? wsums[w - 1] : 0);
    if (i < n) tmp_excl[i] = excl;
    if (threadIdx.x == 1023) blocksums[blockIdx.x] = excl + v;
}

__global__ void scan_sums(int* __restrict__ bs, int nb) {
    __shared__ int wtot[2];
    const int t = threadIdx.x;  // 128 threads
    const int lane = t & 63, w = t >> 6;
    int v = (t < nb) ? bs[t] : 0;
    int s = v;
#pragma unroll
    for (int off = 1; off < 64; off <<= 1) {
        int u = __shfl_up(s, off, 64);
        if (lane >= off) s += u;
    }
    if (lane == 63) wtot[w] = s;
    __syncthreads();
    int excl = s - v + (w == 1 ? wtot[0] : 0);
    if (t < nb) bs[t] = excl;
}

__global__ __launch_bounds__(1024) void scan_apply(const int* __restrict__ tmp_excl,
                                                   const int* __restrict__ bs,
                                                   int* __restrict__ row_ptr,
                                                   int* __restrict__ cursor, int n) {
    const int i = blockIdx.x * 1024 + threadIdx.x;
    if (i < n) {
        int r = tmp_excl[i] + bs[blockIdx.x];
        row_ptr[i] = r;
        cursor[i] = r;
    }
    if (i == 0) row_ptr[n] = NE;
}

// FUSED: blocks [0,NT) run gemm0 (hw = x @ W0, W0 in LDS); blocks [NT,NT+CSRB)
// run csr_fill (pack edges into dst rows, fold norm_src into weights).
// The two halves are independent; fusing overlaps ~40us of gemm with ~50us of
// latency-bound scatter instead of paying them serially.
__global__ __launch_bounds__(256) void csr_gemm0_fused(
        // csr part
        const int* __restrict__ src, const int* __restrict__ dst,
        const float* __restrict__ ew, const float* __restrict__ norm_src,
        int* __restrict__ cursor, float4* __restrict__ cedge,
        // gemm part
        const float* __restrict__ in, const float* __restrict__ W,
        float* __restrict__ out, int n) {
    __shared__ float Ws[128 * 64];
    const int tid = threadIdx.x;

    if (blockIdx.x < NT) {
        // ---- gemm0: 64-row tile, K=128, W in LDS once ----
        for (int i = tid; i < 128 * 16; i += 256) ((float4*)Ws)[i] = ((const float4*)W)[i];
        __syncthreads();

        const int tr = tid >> 4, tc = tid & 15;
        const int row0 = blockIdx.x * 64 + tr * 4;
        const float* xr0 = in + (size_t)min(row0 + 0, n - 1) * 128;
        const float* xr1 = in + (size_t)min(row0 + 1, n - 1) * 128;
        const float* xr2 = in + (size_t)min(row0 + 2, n - 1) * 128;
        const float* xr3 = in + (size_t)min(row0 + 3, n - 1) * 128;

        float4 acc0 = {0, 0, 0, 0}, acc1 = {0, 0, 0, 0}, acc2 = {0, 0, 0, 0}, acc3 = {0, 0, 0, 0};
#pragma unroll 4
        for (int k4 = 0; k4 < 32; ++k4) {
            const int kb = k4 * 4;
            float4 xv0 = *(const float4*)&xr0[kb];
            float4 xv1 = *(const float4*)&xr1[kb];
            float4 xv2 = *(const float4*)&xr2[kb];
            float4 xv3 = *(const float4*)&xr3[kb];
            const float* wb = &Ws[kb * 64 + tc * 4];
            float4 wk;
            wk = *(const float4*)(wb);
            row_fma(acc0, xv0.x, wk); row_fma(acc1, xv1.x, wk); row_fma(acc2, xv2.x, wk); row_fma(acc3, xv3.x, wk);
            wk = *(const float4*)(wb + 64);
            row_fma(acc0, xv0.y, wk); row_fma(acc1, xv1.y, wk); row_fma(acc2, xv2.y, wk); row_fma(acc3, xv3.y, wk);
            wk = *(const float4*)(wb + 128);
            row_fma(acc0, xv0.z, wk); row_fma(acc1, xv1.z, wk); row_fma(acc2, xv2.z, wk); row_fma(acc3, xv3.z, wk);
            wk = *(const float4*)(wb + 192);
            row_fma(acc0, xv0.w, wk); row_fma(acc1, xv1.w, wk); row_fma(acc2, xv2.w, wk); row_fma(acc3, xv3.w, wk);
        }

#pragma unroll
        for (int i = 0; i < 4; ++i) {
            int row = row0 + i;
            if (row < n) {
                float4 o = (i == 0) ? acc0 : (i == 1) ? acc1 : (i == 2) ? acc2 : acc3;
                *(float4*)&out[row * 64 + tc * 4] = o;
            }
        }
    } else {
        // ---- csr_fill: grid-stride over edges with CSRB blocks ----
        int t = (blockIdx.x - NT) * 256 + tid;
        int stride = CSRB * 256;
        for (int e = t; e < NE; e += stride) {
            int s = src[e];
            int d = dst[e];
            float nsv = norm_src[s];
            int slot = atomicAdd(&cursor[d], 1);
            float4 c;
            c.x = __int_as_float(s);
            c.y = ew[e] * nsv;
            c.z = ew[NE + e] * nsv;
            c.w = ew[2 * NE + e] * nsv;
            cedge[slot] = c;
        }
    }
}

// Pure-gather CSR aggregation, one wave per dst node, 8-deep batched loads.
template <int WSEL, bool RELU>
__global__ __launch_bounds__(256) void aggregate(const float* __restrict__ hw,
                                                 const float4* __restrict__ cedge,
                                                 const int* __restrict__ row_ptr,
                                                 const float* __restrict__ norm_dst,
                                                 const float* __restrict__ bias,
                                                 float* __restrict__ outx, int n) {
    const int lane = threadIdx.x & 63;
    const int gw = (blockIdx.x * blockDim.x + threadIdx.x) >> 6;
    const int nw = (gridDim.x * blockDim.x) >> 6;
    const float blane = bias[lane];
    for (int node = gw; node < n; node += nw) {
        int beg = row_ptr[node], end = row_ptr[node + 1];
        float a0 = 0.f, a1 = 0.f, a2 = 0.f, a3 = 0.f;
        int i = beg;
        for (; i + 7 < end; i += 8) {
            float4 c0 = cedge[i + 0], c1 = cedge[i + 1], c2 = cedge[i + 2], c3 = cedge[i + 3];
            float4 c4 = cedge[i + 4], c5 = cedge[i + 5], c6 = cedge[i + 6], c7 = cedge[i + 7];
            float h0 = hw[__float_as_int(c0.x) * 64 + lane];
            float h1 = hw[__float_as_int(c1.x) * 64 + lane];
            float h2 = hw[__float_as_int(c2.x) * 64 + lane];
            float h3 = hw[__float_as_int(c3.x) * 64 + lane];
            float h4 = hw[__float_as_int(c4.x) * 64 + lane];
            float h5 = hw[__float_as_int(c5.x) * 64 + lane];
            float h6 = hw[__float_as_int(c6.x) * 64 + lane];
            float h7 = hw[__float_as_int(c7.x) * 64 + lane];
            a0 = fmaf(h0, (WSEL == 0) ? c0.y : (WSEL == 1) ? c0.z : c0.w, a0);
            a1 = fmaf(h1, (WSEL == 0) ? c1.y : (WSEL == 1) ? c1.z : c1.w, a1);
            a2 = fmaf(h2, (WSEL == 0) ? c2.y : (WSEL == 1) ? c2.z : c2.w, a2);
            a3 = fmaf(h3, (WSEL == 0) ? c3.y : (WSEL == 1) ? c3.z : c3.w, a3);
            a0 = fmaf(h4, (WSEL == 0) ? c4.y : (WSEL == 1) ? c4.z : c4.w, a0);
            a1 = fmaf(h5, (WSEL == 0) ? c5.y : (WSEL == 1) ? c5.z : c5.w, a1);
            a2 = fmaf(h6, (WSEL == 0) ? c6.y : (WSEL == 1) ? c6.z : c6.w, a2);
            a3 = fmaf(h7, (WSEL == 0) ? c7.y : (WSEL == 1) ? c7.z : c7.w, a3);
        }
        for (; i + 1 < end; i += 2) {
            float4 c0 = cedge[i], c1 = cedge[i + 1];
            float h0 = hw[__float_as_int(c0.x) * 64 + lane];
            float h1 = hw[__float_as_int(c1.x) * 64 + lane];
            a0 = fmaf(h0, (WSEL == 0) ? c0.y : (WSEL == 1) ? c0.z : c0.w, a0);
            a1 = fmaf(h1, (WSEL == 0) ? c1.y : (WSEL == 1) ? c1.z : c1.w, a1);
        }
        if (i < end) {
            float4 c0 = cedge[i];
            float h0 = hw[__float_as_int(c0.x) * 64 + lane];
            a0 = fmaf(h0, (WSEL == 0) ? c0.y : (WSEL == 1) ? c0.z : c0.w, a0);
        }
        float a = (a0 + a1) + (a2 + a3);
        float t = fmaf(a, norm_dst[node], blane);
        if (RELU) t = fmaxf(t, 0.f);
        outx[node * 64 + lane] = t;
    }
}

// Streaming 64-row GEMM tile (r7-exact body): W in LDS once, X direct from global.
template <int K>
__global__ __launch_bounds__(256, 5) void gemm_tile(const float* __restrict__ in,
                                                    const float* __restrict__ W,
                                                    float* __restrict__ out, int n) {
    __shared__ float Ws[K * 64];
    const int tid = threadIdx.x;
    for (int i = tid; i < K * 16; i += 256) ((float4*)Ws)[i] = ((const float4*)W)[i];
    __syncthreads();  // the only barrier in the kernel

    const int tr = tid >> 4, tc = tid & 15;
    const int row0 = blockIdx.x * 64 + tr * 4;
    const float* xr0 = in + (size_t)min(row0 + 0, n - 1) * K;
    const float* xr1 = in + (size_t)min(row0 + 1, n - 1) * K;
    const float* xr2 = in + (size_t)min(row0 + 2, n - 1) * K;
    const float* xr3 = in + (size_t)min(row0 + 3, n - 1) * K;

    float4 acc0 = {0, 0, 0, 0}, acc1 = {0, 0, 0, 0}, acc2 = {0, 0, 0, 0}, acc3 = {0, 0, 0, 0};
#pragma unroll 4
    for (int k4 = 0; k4 < K / 4; ++k4) {
        const int kb = k4 * 4;
        float4 xv0 = *(const float4*)&xr0[kb];
        float4 xv1 = *(const float4*)&xr1[kb];
        float4 xv2 = *(const float4*)&xr2[kb];
        float4 xv3 = *(const float4*)&xr3[kb];
        const float* wb = &Ws[kb * 64 + tc * 4];
        float4 wk;
        wk = *(const float4*)(wb);
        row_fma(acc0, xv0.x, wk); row_fma(acc1, xv1.x, wk); row_fma(acc2, xv2.x, wk); row_fma(acc3, xv3.x, wk);
        wk = *(const float4*)(wb + 64);
        row_fma(acc0, xv0.y, wk); row_fma(acc1, xv1.y, wk); row_fma(acc2, xv2.y, wk); row_fma(acc3, xv3.y, wk);
        wk = *(const float4*)(wb + 128);
        row_fma(acc0, xv0.z, wk); row_fma(acc1, xv1.z, wk); row_fma(acc2, xv2.z, wk); row_fma(acc3, xv3.z, wk);
        wk = *(const float4*)(wb + 192);
        row_fma(acc0, xv0.w, wk); row_fma(acc1, xv1.w, wk); row_fma(acc2, xv2.w, wk); row_fma(acc3, xv3.w, wk);
    }

#pragma unroll
    for (int i = 0; i < 4; ++i) {
        int row = row0 + i;
        if (row < n) {
            float4 o = (i == 0) ? acc0 : (i == 1) ? acc1 : (i == 2) ? acc2 : acc3;
            *(float4*)&out[row * 64 + tc * 4] = o;
        }
    }
}

#define ZST 76  // Zs row stride

// 64 pairs per block (grid = 3125), float4-coalesced gather (r13-exact).
__global__ __launch_bounds__(256) void mlp_tile(const float* __restrict__ hfin,
                                                const float* __restrict__ P0,
                                                const float* __restrict__ pb0,
                                                const float* __restrict__ P1,
                                                const float* __restrict__ pb1,
                                                const float* __restrict__ P2,
                                                const float* __restrict__ pb2,
                                                const int* __restrict__ pos_src,
                                                const int* __restrict__ pos_dst,
                                                const int* __restrict__ neg_src,
                                                const int* __restrict__ neg_dst,
                                                float* __restrict__ out, int P) {
    __shared__ float Zs[64][ZST];
    __shared__ float pb0s[64], pb1s[64], P2s[64];
    __shared__ int pas[64], pbs[64];
    const int tid = threadIdx.x;
    const int base = blockIdx.x << 6;
    if (tid < 64) {
        pb0s[tid] = pb0[tid];
        pb1s[tid] = pb1[tid];
        P2s[tid] = P2[tid];
        int p = base + tid;
        pas[tid] = (p < P) ? pos_src[p] : neg_src[p - P];
        pbs[tid] = (p < P) ? pos_dst[p] : neg_dst[p - P];
    }
    const float pb2v = pb2[0];
    const int lane = tid & 63, w = tid >> 6;
    const int tr = tid >> 4, tc = tid & 15;
    __syncthreads();

    // gather + product, float4-coalesced: wave w owns pairs [w*16, w*16+16).
    {
        const int sub = lane >> 4;       // 0..3: which pair within the quad
        const int c4 = (lane & 15) * 4;  // feature column base
        float4 ha[4], hb[4];
#pragma unroll
        for (int r = 0; r < 4; ++r) {
            const int pi = w * 16 + r * 4 + sub;
            ha[r] = *(const float4*)&hfin[pas[pi] * 64 + c4];
            hb[r] = *(const float4*)&hfin[pbs[pi] * 64 + c4];
        }
#pragma unroll
        for (int r = 0; r < 4; ++r) {
            const int pi = w * 16 + r * 4 + sub;
            float4 z;
            z.x = ha[r].x * hb[r].x;
            z.y = ha[r].y * hb[r].y;
            z.z = ha[r].z * hb[r].z;
            z.w = ha[r].w * hb[r].w;
            *(float4*)&Zs[pi][c4] = z;
        }
    }
    __syncthreads();

    // layer 0: Z1 = relu(Z @ P0 + pb0)
    float4 acc0, acc1, acc2, acc3;
    {
        float4 binit = *(const float4*)&pb0s[tc * 4];
        acc0 = binit; acc1 = binit; acc2 = binit; acc3 = binit;
    }
#pragma unroll 4
    for (int k4 = 0; k4 < 16; ++k4) {
        const int kb = k4 * 4;
        float4 xv0 = *(const float4*)&Zs[tr * 4 + 0][kb];
        float4 xv1 = *(const float4*)&Zs[tr * 4 + 1][kb];
        float4 xv2 = *(const float4*)&Zs[tr * 4 + 2][kb];
        float4 xv3 = *(const float4*)&Zs[tr * 4 + 3][kb];
        const float* wb = &P0[kb * 64 + tc * 4];
        float4 wk;
        wk = *(const float4*)(wb);
        row_fma(acc0, xv0.x, wk); row_fma(acc1, xv1.x, wk); row_fma(acc2, xv2.x, wk); row_fma(acc3, xv3.x, wk);
        wk = *(const float4*)(wb + 64);
        row_fma(acc0, xv0.y, wk); row_fma(acc1, xv1.y, wk); row_fma(acc2, xv2.y, wk); row_fma(acc3, xv3.y, wk);
        wk = *(const float4*)(wb + 128);
        row_fma(acc0, xv0.z, wk); row_fma(acc1, xv1.z, wk); row_fma(acc2, xv2.z, wk); row_fma(acc3, xv3.z, wk);
        wk = *(const float4*)(wb + 192);
        row_fma(acc0, xv0.w, wk); row_fma(acc1, xv1.w, wk); row_fma(acc2, xv2.w, wk); row_fma(acc3, xv3.w, wk);
    }
    __syncthreads();
#pragma unroll
    for (int i = 0; i < 4; ++i) {
        float4 o = (i == 0) ? acc0 : (i == 1) ? acc1 : (i == 2) ? acc2 : acc3;
        o.x = fmaxf(o.x, 0.f); o.y = fmaxf(o.y, 0.f); o.z = fmaxf(o.z, 0.f); o.w = fmaxf(o.w, 0.f);
        *(float4*)&Zs[tr * 4 + i][tc * 4] = o;
    }
    __syncthreads();

    // layer 1: Z2 = relu(Z1 @ P1 + pb1)
    {
        float4 binit = *(const float4*)&pb1s[tc * 4];
        acc0 = binit; acc1 = binit; acc2 = binit; acc3 = binit;
    }
#pragma unroll 4
    for (int k4 = 0; k4 < 16; ++k4) {
        const int kb = k4 * 4;
        float4 xv0 = *(const float4*)&Zs[tr * 4 + 0][kb];
        float4 xv1 = *(const float4*)&Zs[tr * 4 + 1][kb];
        float4 xv2 = *(const float4*)&Zs[tr * 4 + 2][kb];
        float4 xv3 = *(const float4*)&Zs[tr * 4 + 3][kb];
        const float* wb = &P1[kb * 64 + tc * 4];
        float4 wk;
        wk = *(const float4*)(wb);
        row_fma(acc0, xv0.x, wk); row_fma(acc1, xv1.x, wk); row_fma(acc2, xv2.x, wk); row_fma(acc3, xv3.x, wk);
        wk = *(const float4*)(wb + 64);
        row_fma(acc0, xv0.y, wk); row_fma(acc1, xv1.y, wk); row_fma(acc2, xv2.y, wk); row_fma(acc3, xv3.y, wk);
        wk = *(const float4*)(wb + 128);
        row_fma(acc0, xv0.z, wk); row_fma(acc1, xv1.z, wk); row_fma(acc2, xv2.z, wk); row_fma(acc3, xv3.z, wk);
        wk = *(const float4*)(wb + 192);
        row_fma(acc0, xv0.w, wk); row_fma(acc1, xv1.w, wk); row_fma(acc2, xv2.w, wk); row_fma(acc3, xv3.w, wk);
    }
    __syncthreads();
#pragma unroll
    for (int i = 0; i < 4; ++i) {
        float4 o = (i == 0) ? acc0 : (i == 1) ? acc1 : (i == 2) ? acc2 : acc3;
        o.x = fmaxf(o.x, 0.f); o.y = fmaxf(o.y, 0.f); o.z = fmaxf(o.z, 0.f); o.w = fmaxf(o.w, 0.f);
        *(float4*)&Zs[tr * 4 + i][tc * 4] = o;
    }
    __syncthreads();

    // final GEMV: out[p] = Z2[p] . P2 + pb2   (4 lanes per pair, 16 k each)
    {
        int p = tid >> 2, kq = tid & 3;
        float s = 0.f;
#pragma unroll
        for (int i = 0; i < 16; ++i) s = fmaf(Zs[p][kq * 16 + i], P2s[kq * 16 + i], s);
        s += __shfl_xor(s, 1, 64);
        s += __shfl_xor(s, 2, 64);
        if (kq == 0) out[base + p] = s + pb2v;
    }
}

extern "C" void kernel_launch(void* const* d_in, const int* in_sizes, int n_in,
                              void* d_out, int out_size, void* d_ws, size_t ws_size,
                              hipStream_t stream) {
    const float* x     = (const float*)d_in[0];
    const float* ew    = (const float*)d_in[1];  // (3, E)
    const int* src     = (const int*)d_in[2];
    const int* dst     = (const int*)d_in[3];
    const int* pos_src = (const int*)d_in[4];
    const int* pos_dst = (const int*)d_in[5];
    const int* neg_src = (const int*)d_in[6];
    const int* neg_dst = (const int*)d_in[7];
    const float* W0    = (const float*)d_in[8];
    const float* b0    = (const float*)d_in[9];
    const float* W1    = (const float*)d_in[10];
    const float* b1    = (const float*)d_in[11];
    const float* W2    = (const float*)d_in[12];
    const float* b2    = (const float*)d_in[13];
    const float* P0    = (const float*)d_in[14];
    const float* pb0   = (const float*)d_in[15];
    const float* P1    = (const float*)d_in[16];
    const float* pb1   = (const float*)d_in[17];
    const float* P2    = (const float*)d_in[18];
    const float* pb2   = (const float*)d_in[19];
    float* out = (float*)d_out;

    float* ws = (float*)d_ws;
    float* norm_src = ws;                     // N
    float* norm_dst = ws + 100000;            // N
    int* cursor     = (int*)(ws + 200000);    // N
    int* deg_in     = (int*)(ws + 300000);    // N
    int* row_ptr    = (int*)(ws + 400000);    // N+1
    float4* cedge   = (float4*)(ws + 500004); // E
    float* hw       = ws + 4500004;           // N*64
    float* agg      = ws + 10900004;          // N*64

    // pre-layer0 scratch inside hw region... NOTE: hw is now written by the fused
    // kernel's gemm half, so scan scratch must be dead before the fused launch. It is:
    // repl/tmp_excl/blocksums are consumed by reduce_norm/scan_* which all precede it.
    int* repl      = (int*)hw;            // 16*NN ints
    int* tmp_excl  = (int*)hw + 16 * NN;  // NN
    int* blocksums = (int*)hw + 17 * NN;  // SCAN_NB

    hipMemsetAsync(repl, 0, 16 * NN * sizeof(int), stream);
    deg_kernel<<<(NE / 4 + 255) / 256, 256, 0, stream>>>((const int4*)src, (const int4*)dst,
                                                         repl, NE / 4);
    reduce_norm_kernel<<<(NN + 255) / 256, 256, 0, stream>>>(repl, norm_src, norm_dst, deg_in, NN);
    scan_block<<<SCAN_NB, 1024, 0, stream>>>(deg_in, tmp_excl, blocksums, NN);
    scan_sums<<<1, 128, 0, stream>>>(blocksums, SCAN_NB);
    scan_apply<<<SCAN_NB, 1024, 0, stream>>>(tmp_excl, blocksums, row_ptr, cursor, NN);

    // FUSED: csr_fill (2048 blocks) overlapped with gemm0 (1563 blocks)
    csr_gemm0_fused<<<NT + CSRB, 256, 0, stream>>>(src, dst, ew, norm_src, cursor, cedge,
                                                   x, W0, hw, NN);

    aggregate<0, true><<<4096, 256, 0, stream>>>(hw, cedge, row_ptr, norm_dst, b0, agg, NN);
    // layer 1
    gemm_tile<64><<<NT, 256, 0, stream>>>(agg, W1, hw, NN);
    aggregate<1, true><<<4096, 256, 0, stream>>>(hw, cedge, row_ptr, norm_dst, b1, agg, NN);
    // layer 2 (final, no relu)
    gemm_tile<64><<<NT, 256, 0, stream>>>(agg, W2, hw, NN);
    aggregate<2, false><<<4096, 256, 0, stream>>>(hw, cedge, row_ptr, norm_dst, b2, agg, NN);

    // MLP over pos & neg pairs (64 pairs per block)
    mlp_tile<<<(2 * NP) / 64, 256, 0, stream>>>(agg, P0, pb0, P1, pb1, P2, pb2,
                                                pos_src, pos_dst, neg_src, neg_dst, out, NP);
}